// Round 3
// baseline (655.816 us; speedup 1.0000x reference)
//
#include <hip/hip_runtime.h>
#include <hip/hip_bf16.h>
#include <math.h>

#define B_  4
#define D_  512
#define L_  8192
#define CH_ 512
#define M_  1024   // interleaved (h,g) rows

// ---------------------------------------------------------------------------
// Kernel 1: normalize h_w / g_w rows, interleave into Wn[1024][512] f32.
// Row 2*ch = h_w[ch]/(1e-4*sqrt(512)+||.||), row 2*ch+1 = g_w[ch-2]/(...).
// ---------------------------------------------------------------------------
__global__ __launch_bounds__(256)
void prep_kernel(const float* __restrict__ h_w, const float* __restrict__ g_w,
                 float* __restrict__ Wn) {
    __shared__ float red[4];
    const int ch = blockIdx.x, t = threadIdx.x;
    {
        float v0 = h_w[ch * 512 + t], v1 = h_w[ch * 512 + t + 256];
        float ss = v0 * v0 + v1 * v1;
        #pragma unroll
        for (int off = 32; off > 0; off >>= 1) ss += __shfl_down(ss, off, 64);
        if ((t & 63) == 0) red[t >> 6] = ss;
        __syncthreads();
        float tot = red[0] + red[1] + red[2] + red[3];
        float scale = 1.f / (sqrtf(tot) + 1e-4f * sqrtf(512.f));
        Wn[(size_t)(2 * ch) * 512 + t]       = v0 * scale;
        Wn[(size_t)(2 * ch) * 512 + t + 256] = v1 * scale;
    }
    __syncthreads();
    if (ch >= 2) {
        float v0 = g_w[(ch - 2) * 512 + t], v1 = g_w[(ch - 2) * 512 + t + 256];
        float ss = v0 * v0 + v1 * v1;
        #pragma unroll
        for (int off = 32; off > 0; off >>= 1) ss += __shfl_down(ss, off, 64);
        if ((t & 63) == 0) red[t >> 6] = ss;
        __syncthreads();
        float tot = red[0] + red[1] + red[2] + red[3];
        float scale = 1.f / (sqrtf(tot) + 1e-4f * sqrtf(512.f));
        Wn[(size_t)(2 * ch + 1) * 512 + t]       = v0 * scale;
        Wn[(size_t)(2 * ch + 1) * 512 + t + 256] = v1 * scale;
    } else {
        Wn[(size_t)(2 * ch + 1) * 512 + t]       = 0.f;
        Wn[(size_t)(2 * ch + 1) * 512 + t + 256] = 0.f;
    }
}

// ---------------------------------------------------------------------------
// Kernel 2: depthwise 5-tap conv, pad=2, mp-normalized weights, f32 out.
// ---------------------------------------------------------------------------
__global__ __launch_bounds__(256)
void conv_kernel(const float* __restrict__ x_b, const float* __restrict__ cw,
                 float* __restrict__ Cb) {
    __shared__ float xs[8200];   // data at xs[4 + l], zero pads at both ends
    const int d = blockIdx.x;
    const int t = threadIdx.x;
    const float* xr = x_b + (size_t)d * L_;
    #pragma unroll
    for (int i = 0; i < 8; ++i) {
        float4 v = *(const float4*)&xr[(i * 256 + t) * 4];
        *(float4*)&xs[4 + (i * 256 + t) * 4] = v;
    }
    if (t < 4) xs[t] = 0.f;
    if (t >= 252) xs[8196 + (t - 252)] = 0.f;
    float w0 = cw[d * 5 + 0], w1 = cw[d * 5 + 1], w2 = cw[d * 5 + 2],
          w3 = cw[d * 5 + 3], w4 = cw[d * 5 + 4];
    float ss = w0 * w0 + w1 * w1 + w2 * w2 + w3 * w3 + w4 * w4;
    float scale = 1.f / (sqrtf(ss) + 1e-4f * sqrtf(5.f));
    w0 *= scale; w1 *= scale; w2 *= scale; w3 *= scale; w4 *= scale;
    __syncthreads();
    #pragma unroll
    for (int i = 0; i < 32; ++i) {
        int l = i * 256 + t;
        float acc = w0 * xs[l + 2] + w1 * xs[l + 3] + w2 * xs[l + 4]
                  + w3 * xs[l + 5] + w4 * xs[l + 6];
        Cb[(size_t)d * L_ + l] = acc;
    }
}

// ---------------------------------------------------------------------------
// Kernel 3: f32 VALU GEMM: rows even=h odd=g; outputs RAW h and g
// (gate math moved into the log-space scan). ch0 g=-1000, ch1 g=+1000.
// ---------------------------------------------------------------------------
__global__ __launch_bounds__(256)
void gemm_f32_kernel(const float* __restrict__ Wn, const float* __restrict__ Cb,
                     float* __restrict__ Hout, float* __restrict__ Gout) {
    __shared__ float As2[16][68];   // [k][m], padded
    __shared__ float Bs[16][64];    // [k][n]
    const int t = threadIdx.x;
    const int tn = t & 15, tm = t >> 4;
    const int mBase = blockIdx.x * 64, nBase = blockIdx.y * 64;

    float acc[4][4] = {};

    const int arow = t >> 2, ak = (t & 3) * 4;    // A: 64 rows x 16 k
    const int bkr = t >> 4, bnc = (t & 15) * 4;   // B: 16 k x 64 n

    for (int k0 = 0; k0 < 512; k0 += 16) {
        float4 av = *(const float4*)&Wn[(size_t)(mBase + arow) * 512 + k0 + ak];
        As2[ak + 0][arow] = av.x;
        As2[ak + 1][arow] = av.y;
        As2[ak + 2][arow] = av.z;
        As2[ak + 3][arow] = av.w;
        float4 bv = *(const float4*)&Cb[(size_t)(k0 + bkr) * L_ + nBase + bnc];
        *(float4*)&Bs[bkr][bnc] = bv;
        __syncthreads();
        #pragma unroll
        for (int kk = 0; kk < 16; ++kk) {
            float4 a4 = *(const float4*)&As2[kk][tm * 4];
            float4 b4 = *(const float4*)&Bs[kk][tn * 4];
            acc[0][0] += a4.x * b4.x; acc[0][1] += a4.x * b4.y;
            acc[0][2] += a4.x * b4.z; acc[0][3] += a4.x * b4.w;
            acc[1][0] += a4.y * b4.x; acc[1][1] += a4.y * b4.y;
            acc[1][2] += a4.y * b4.z; acc[1][3] += a4.y * b4.w;
            acc[2][0] += a4.z * b4.x; acc[2][1] += a4.z * b4.y;
            acc[2][2] += a4.z * b4.z; acc[2][3] += a4.z * b4.w;
            acc[3][0] += a4.w * b4.x; acc[3][1] += a4.w * b4.y;
            acc[3][2] += a4.w * b4.z; acc[3][3] += a4.w * b4.w;
        }
        __syncthreads();
    }

    const int row0 = mBase + tm * 4;
    #pragma unroll
    for (int pp = 0; pp < 2; ++pp) {
        int ch = (row0 >> 1) + pp;
        #pragma unroll
        for (int j = 0; j < 4; ++j) {
            float hv = acc[2 * pp][j], gv = acc[2 * pp + 1][j];
            if (ch == 0)      gv = -1000.f;
            else if (ch == 1) gv =  1000.f;
            size_t off = (size_t)ch * L_ + (nBase + tn * 4 + j);
            Hout[off] = hv;
            Gout[off] = gv;
        }
    }
}

// ---------------------------------------------------------------------------
// Kernel 4: f32 LOG-SPACE scan replicating the reference numerics:
//   log_a = log_sigmoid(-g); A* = cumsum(log_a)
//   z = log_sigmoid(g) + log(max(|h|,1e-6)) - A*   (sign tracked separately)
//   LC = log-cum-sum-exp(z)  (signed log-magnitude combine)
//   o  = sign * exp(A* + LC)
// One block per (b,ch) row; h lives in out (in-place).
// ---------------------------------------------------------------------------
struct LV { float re, sg; };

__device__ __forceinline__ float logsig(float x) {
    // stable log_sigmoid: min(x,0) - log1p(exp(-|x|))
    return fminf(x, 0.f) - log1pf(expf(-fabsf(x)));
}

__device__ __forceinline__ LV lcomb(LV a, LV b) {
    float m  = fmaxf(a.re, b.re);
    float ms = (m > -3.0e38f) ? m : 0.f;      // m_safe (guards -inf,-inf)
    float s  = a.sg * expf(a.re - ms) + b.sg * expf(b.re - ms);
    LV r;
    r.re = ms + logf(fabsf(s));               // log(0) -> -inf: ok
    r.sg = (s < 0.f) ? -1.f : 1.f;
    return r;
}

__global__ __launch_bounds__(256)
void logscan_kernel(const float* __restrict__ G, float* __restrict__ HO) {
    __shared__ float sA[256];
    __shared__ float sRe[256], sSg[256];
    const int row = blockIdx.x;
    const int t = threadIdx.x;
    const float* gp = G + (size_t)row * L_;
    float* hp = HO + (size_t)row * L_;
    float hv[32], gv[32];
    #pragma unroll
    for (int i = 0; i < 8; ++i) {
        *(float4*)&hv[i * 4] = *(const float4*)&hp[t * 32 + i * 4];
        *(float4*)&gv[i * 4] = *(const float4*)&gp[t * 32 + i * 4];
    }
    // ---- phase 1: A_star = inclusive cumsum of log_sigmoid(-g) ----
    float la[32];
    float run = 0.f;
    #pragma unroll
    for (int i = 0; i < 32; ++i) { run += logsig(-gv[i]); la[i] = run; }
    sA[t] = run;
    __syncthreads();
    float v = run;
    for (int off = 1; off < 256; off <<= 1) {
        float p = (t >= off) ? sA[t - off] : 0.f;
        __syncthreads();
        v += p;
        sA[t] = v;
        __syncthreads();
    }
    const float ex = (t == 0) ? 0.f : sA[t - 1];
    // ---- phase 2: z and signed log-cumsum-exp ----
    LV lr[32];
    LV p = { -INFINITY, 1.f };
    #pragma unroll
    for (int i = 0; i < 32; ++i) {
        float As = ex + la[i];
        float zr = logsig(gv[i]) + logf(fmaxf(fabsf(hv[i]), 1e-6f)) - As;
        LV zi; zi.re = zr; zi.sg = (hv[i] < 0.f) ? -1.f : 1.f;
        p = lcomb(p, zi);
        lr[i] = p;
        la[i] = As;            // stash A_star for the epilogue
    }
    sRe[t] = p.re; sSg[t] = p.sg;
    __syncthreads();
    LV q = p;
    for (int off = 1; off < 256; off <<= 1) {
        LV r = { -INFINITY, 1.f };
        if (t >= off) { r.re = sRe[t - off]; r.sg = sSg[t - off]; }
        __syncthreads();
        q = lcomb(r, q);
        sRe[t] = q.re; sSg[t] = q.sg;
        __syncthreads();
    }
    LV pref = { -INFINITY, 1.f };
    if (t > 0) { pref.re = sRe[t - 1]; pref.sg = sSg[t - 1]; }
    #pragma unroll
    for (int i = 0; i < 32; ++i) {
        LV f = lcomb(pref, lr[i]);
        hv[i] = f.sg * expf(la[i] + f.re);
    }
    #pragma unroll
    for (int i = 0; i < 8; ++i)
        *(float4*)&hp[t * 32 + i * 4] = *(const float4*)&hv[i * 4];
}

// ---------------------------------------------------------------------------
extern "C" void kernel_launch(void* const* d_in, const int* in_sizes, int n_in,
                              void* d_out, int out_size, void* d_ws, size_t ws_size,
                              hipStream_t stream) {
    const float* x      = (const float*)d_in[0];
    const float* conv_w = (const float*)d_in[1];
    const float* h_w    = (const float*)d_in[2];
    const float* g_w    = (const float*)d_in[3];
    float* out = (float*)d_out;
    char* ws = (char*)d_ws;

    // ws layout (34 MB): c_b f32 16MB | Wn f32 2MB | g_b f32 16MB
    float* c_b = (float*)ws;
    float* Wn  = (float*)(ws + (size_t)16 * 1024 * 1024);
    float* g_b = (float*)(ws + (size_t)18 * 1024 * 1024);

    prep_kernel<<<512, 256, 0, stream>>>(h_w, g_w, Wn);
    for (int b = 0; b < B_; ++b) {
        const float* x_b   = x   + (size_t)b * D_ * L_;
        float*       out_b = out + (size_t)b * CH_ * L_;
        conv_kernel<<<D_, 256, 0, stream>>>(x_b, conv_w, c_b);
        gemm_f32_kernel<<<dim3(M_ / 64, L_ / 64), 256, 0, stream>>>(Wn, c_b, out_b, g_b);
        logscan_kernel<<<CH_, 256, 0, stream>>>(g_b, out_b);
    }
}

// Round 5
// 411.675 us; speedup vs baseline: 1.5930x; 1.5930x over previous
//
#include <hip/hip_runtime.h>
#include <hip/hip_bf16.h>
#include <math.h>

typedef float f32x4 __attribute__((ext_vector_type(4)));
typedef short s16x8 __attribute__((ext_vector_type(8)));

#define B_  4
#define D_  512
#define L_  8192
#define CH_ 512
#define M_  1024   // interleaved (h,g) rows

__device__ __forceinline__ unsigned short f2bf(float f) {
    union { float f; unsigned u; } v; v.f = f;
    unsigned r = v.u + 0x7FFFu + ((v.u >> 16) & 1u);
    return (unsigned short)(r >> 16);
}

// ---------------------------------------------------------------------------
// Kernel 1: normalize h_w / g_w rows, interleave into Wn[1024][512] bf16.
// ---------------------------------------------------------------------------
__global__ __launch_bounds__(256)
void prep_kernel(const float* __restrict__ h_w, const float* __restrict__ g_w,
                 unsigned short* __restrict__ Wn) {
    __shared__ float red[4];
    const int ch = blockIdx.x, t = threadIdx.x;
    {
        float v0 = h_w[ch * 512 + t], v1 = h_w[ch * 512 + t + 256];
        float ss = v0 * v0 + v1 * v1;
        #pragma unroll
        for (int off = 32; off > 0; off >>= 1) ss += __shfl_down(ss, off, 64);
        if ((t & 63) == 0) red[t >> 6] = ss;
        __syncthreads();
        float tot = red[0] + red[1] + red[2] + red[3];
        float scale = 1.f / (sqrtf(tot) + 1e-4f * sqrtf(512.f));
        Wn[(size_t)(2 * ch) * 512 + t]       = f2bf(v0 * scale);
        Wn[(size_t)(2 * ch) * 512 + t + 256] = f2bf(v1 * scale);
    }
    __syncthreads();
    if (ch >= 2) {
        float v0 = g_w[(ch - 2) * 512 + t], v1 = g_w[(ch - 2) * 512 + t + 256];
        float ss = v0 * v0 + v1 * v1;
        #pragma unroll
        for (int off = 32; off > 0; off >>= 1) ss += __shfl_down(ss, off, 64);
        if ((t & 63) == 0) red[t >> 6] = ss;
        __syncthreads();
        float tot = red[0] + red[1] + red[2] + red[3];
        float scale = 1.f / (sqrtf(tot) + 1e-4f * sqrtf(512.f));
        Wn[(size_t)(2 * ch + 1) * 512 + t]       = f2bf(v0 * scale);
        Wn[(size_t)(2 * ch + 1) * 512 + t + 256] = f2bf(v1 * scale);
    } else {
        Wn[(size_t)(2 * ch + 1) * 512 + t]       = 0;
        Wn[(size_t)(2 * ch + 1) * 512 + t + 256] = 0;
    }
}

// ---------------------------------------------------------------------------
// Kernel 2: depthwise 5-tap conv, pad=2, mp-normalized weights, bf16 out.
// ---------------------------------------------------------------------------
__global__ __launch_bounds__(256)
void conv_kernel(const float* __restrict__ x, const float* __restrict__ cw,
                 unsigned short* __restrict__ C) {
    __shared__ float xs[8200];   // data at xs[4 + l], zero pads at both ends
    const int row = blockIdx.x;          // b*512 + d
    const int d   = row & 511;
    const int t   = threadIdx.x;
    const float* xr = x + (size_t)row * L_;
    #pragma unroll
    for (int i = 0; i < 8; ++i) {
        float4 v = *(const float4*)&xr[(i * 256 + t) * 4];
        *(float4*)&xs[4 + (i * 256 + t) * 4] = v;
    }
    if (t < 4) xs[t] = 0.f;
    if (t >= 252) xs[8196 + (t - 252)] = 0.f;
    float w0 = cw[d * 5 + 0], w1 = cw[d * 5 + 1], w2 = cw[d * 5 + 2],
          w3 = cw[d * 5 + 3], w4 = cw[d * 5 + 4];
    float ss = w0 * w0 + w1 * w1 + w2 * w2 + w3 * w3 + w4 * w4;
    float scale = 1.f / (sqrtf(ss) + 1e-4f * sqrtf(5.f));
    w0 *= scale; w1 *= scale; w2 *= scale; w3 *= scale; w4 *= scale;
    __syncthreads();
    #pragma unroll
    for (int i = 0; i < 32; ++i) {
        int l = i * 256 + t;
        float acc = w0 * xs[l + 2] + w1 * xs[l + 3] + w2 * xs[l + 4]
                  + w3 * xs[l + 5] + w4 * xs[l + 6];
        C[(size_t)row * L_ + l] = f2bf(acc);
    }
}

// ---------------------------------------------------------------------------
// Kernel 3: bf16 MFMA GEMM, raw h/g epilogue (ch0 g=-1000, ch1 g=+1000).
// ---------------------------------------------------------------------------
__global__ __launch_bounds__(256)
void gemm_kernel(const unsigned short* __restrict__ Wn,
                 const unsigned short* __restrict__ C,
                 float* __restrict__ Hout, float* __restrict__ Gout) {
    __shared__ unsigned short As[64 * 40];   // [row][k] padded stride 40
    __shared__ unsigned short Bs[64 * 40];   // [n][k]   padded stride 40
    const int t = threadIdx.x;
    const int lane = t & 63, w = t >> 6;
    const int mBase = blockIdx.x * 64;
    const int nBase = blockIdx.y * 64;
    const int b = blockIdx.z;

    f32x4 acc00 = {0,0,0,0}, acc01 = {0,0,0,0}, acc10 = {0,0,0,0}, acc11 = {0,0,0,0};

    const int arow = t >> 2, akp = (t & 3) * 8;
    const int bk = t >> 3, bn0 = (t & 7) * 8;
    const size_t cBase = ((size_t)b * D_) * L_ + nBase;
    const int wrow = (w >> 1) * 32, wcol = (w & 1) * 32;

    for (int k0 = 0; k0 < 512; k0 += 32) {
        s16x8 av = *(const s16x8*)&Wn[(size_t)(mBase + arow) * 512 + k0 + akp];
        *(s16x8*)&As[arow * 40 + akp] = av;
        s16x8 bv = *(const s16x8*)&C[cBase + (size_t)(k0 + bk) * L_ + bn0];
        #pragma unroll
        for (int j = 0; j < 8; ++j)
            Bs[(bn0 + j) * 40 + bk] = (unsigned short)bv[j];
        __syncthreads();
        const int ar0 = (wrow + (lane & 15)) * 40 + (lane >> 4) * 8;
        const int br0 = (wcol + (lane & 15)) * 40 + (lane >> 4) * 8;
        s16x8 a0 = *(const s16x8*)&As[ar0];
        s16x8 a1 = *(const s16x8*)&As[ar0 + 16 * 40];
        s16x8 b0 = *(const s16x8*)&Bs[br0];
        s16x8 b1 = *(const s16x8*)&Bs[br0 + 16 * 40];
        acc00 = __builtin_amdgcn_mfma_f32_16x16x32_bf16(a0, b0, acc00, 0, 0, 0);
        acc01 = __builtin_amdgcn_mfma_f32_16x16x32_bf16(a0, b1, acc01, 0, 0, 0);
        acc10 = __builtin_amdgcn_mfma_f32_16x16x32_bf16(a1, b0, acc10, 0, 0, 0);
        acc11 = __builtin_amdgcn_mfma_f32_16x16x32_bf16(a1, b1, acc11, 0, 0, 0);
        __syncthreads();
    }

    f32x4 accs[2][2] = {{acc00, acc01}, {acc10, acc11}};
    #pragma unroll
    for (int fr = 0; fr < 2; ++fr)
    #pragma unroll
    for (int fc = 0; fc < 2; ++fc) {
        f32x4 acc = accs[fr][fc];
        int gR = mBase + wrow + fr * 16 + ((lane >> 4) * 4);   // multiple of 4
        int l  = nBase + wcol + fc * 16 + (lane & 15);
        #pragma unroll
        for (int p = 0; p < 2; ++p) {
            float hv = acc[2 * p], gv = acc[2 * p + 1];
            int ch = (gR >> 1) + p;
            if (ch == 0)      gv = -1000.f;
            else if (ch == 1) gv =  1000.f;
            size_t off = ((size_t)b * CH_ + ch) * L_ + l;
            Hout[off] = hv;
            Gout[off] = gv;
        }
    }
}

// ---------------------------------------------------------------------------
// Kernel 3b: recompute h[b][1][:] in full f32 (ch1 output = sign*exp(q) with
// q = log|h| quantized to 0.5 ULP against 1000*(t+1) -> needs f32-exact h;
// bf16 GEMM noise flips the quantization (measured: absmax = e^0.5-1)).
// Inline depthwise-conv recompute from x, sequential d-order (matches the
// validated round-3 f32 summation order).
// ---------------------------------------------------------------------------
__global__ __launch_bounds__(256)
void fixch1_kernel(const float* __restrict__ x, const float* __restrict__ cw,
                   const float* __restrict__ h_w, float* __restrict__ Hout) {
    __shared__ float wc[512][5];
    __shared__ float w1n[512];
    __shared__ float red[4];
    const int b = blockIdx.y;
    const int l = blockIdx.x * 256 + threadIdx.x;
    const int t = threadIdx.x;
    for (int d = t; d < 512; d += 256) {
        float a0 = cw[d * 5 + 0], a1 = cw[d * 5 + 1], a2 = cw[d * 5 + 2],
              a3 = cw[d * 5 + 3], a4 = cw[d * 5 + 4];
        float ss = a0 * a0 + a1 * a1 + a2 * a2 + a3 * a3 + a4 * a4;
        float sc = 1.f / (sqrtf(ss) + 1e-4f * sqrtf(5.f));
        wc[d][0] = a0 * sc; wc[d][1] = a1 * sc; wc[d][2] = a2 * sc;
        wc[d][3] = a3 * sc; wc[d][4] = a4 * sc;
    }
    {
        float v0 = h_w[512 + t], v1 = h_w[512 + t + 256];  // h_w row 1
        float ss = v0 * v0 + v1 * v1;
        #pragma unroll
        for (int off = 32; off > 0; off >>= 1) ss += __shfl_down(ss, off, 64);
        if ((t & 63) == 0) red[t >> 6] = ss;
        __syncthreads();
        float tot = red[0] + red[1] + red[2] + red[3];
        float sc = 1.f / (sqrtf(tot) + 1e-4f * sqrtf(512.f));
        w1n[t] = v0 * sc; w1n[t + 256] = v1 * sc;
    }
    __syncthreads();
    float acc = 0.f;
    const float* xb = x + (size_t)b * D_ * L_;
    for (int d = 0; d < 512; ++d) {
        const float* xr = xb + (size_t)d * L_;
        float x0 = (l >= 2)      ? xr[l - 2] : 0.f;
        float x1 = (l >= 1)      ? xr[l - 1] : 0.f;
        float x2 = xr[l];
        float x3 = (l + 1 < L_)  ? xr[l + 1] : 0.f;
        float x4 = (l + 2 < L_)  ? xr[l + 2] : 0.f;
        float cv = wc[d][0] * x0 + wc[d][1] * x1 + wc[d][2] * x2
                 + wc[d][3] * x3 + wc[d][4] * x4;
        acc += w1n[d] * cv;
    }
    Hout[((size_t)b * CH_ + 1) * L_ + l] = acc;
}

// ---------------------------------------------------------------------------
// Kernel 4: f32 LOG-SPACE scan replicating the reference numerics.
// ---------------------------------------------------------------------------
struct LV { float re, sg; };

__device__ __forceinline__ float logsig(float x) {
    return fminf(x, 0.f) - log1pf(expf(-fabsf(x)));
}

__device__ __forceinline__ LV lcomb(LV a, LV b) {
    float m  = fmaxf(a.re, b.re);
    float ms = (m > -3.0e38f) ? m : 0.f;      // m_safe (guards -inf,-inf)
    float s  = a.sg * expf(a.re - ms) + b.sg * expf(b.re - ms);
    LV r;
    r.re = ms + logf(fabsf(s));
    r.sg = (s < 0.f) ? -1.f : 1.f;
    return r;
}

__global__ __launch_bounds__(256)
void logscan_kernel(const float* __restrict__ G, float* __restrict__ HO) {
    __shared__ float sA[256];
    __shared__ float sRe[256], sSg[256];
    const int row = blockIdx.x;
    const int t = threadIdx.x;
    const float* gp = G + (size_t)row * L_;
    float* hp = HO + (size_t)row * L_;
    float hv[32], gv[32];
    #pragma unroll
    for (int i = 0; i < 8; ++i) {
        *(float4*)&hv[i * 4] = *(const float4*)&hp[t * 32 + i * 4];
        *(float4*)&gv[i * 4] = *(const float4*)&gp[t * 32 + i * 4];
    }
    // ---- phase 1: A_star = inclusive cumsum of log_sigmoid(-g) ----
    float la[32];
    float run = 0.f;
    #pragma unroll
    for (int i = 0; i < 32; ++i) { run += logsig(-gv[i]); la[i] = run; }
    sA[t] = run;
    __syncthreads();
    float v = run;
    for (int off = 1; off < 256; off <<= 1) {
        float p = (t >= off) ? sA[t - off] : 0.f;
        __syncthreads();
        v += p;
        sA[t] = v;
        __syncthreads();
    }
    const float ex = (t == 0) ? 0.f : sA[t - 1];
    // ---- phase 2: z and signed log-cumsum-exp ----
    LV lr[32];
    LV p = { -INFINITY, 1.f };
    #pragma unroll
    for (int i = 0; i < 32; ++i) {
        float As = ex + la[i];
        float zr = logsig(gv[i]) + logf(fmaxf(fabsf(hv[i]), 1e-6f)) - As;
        LV zi; zi.re = zr; zi.sg = (hv[i] < 0.f) ? -1.f : 1.f;
        p = lcomb(p, zi);
        lr[i] = p;
        la[i] = As;            // stash A_star for the epilogue
    }
    sRe[t] = p.re; sSg[t] = p.sg;
    __syncthreads();
    LV q = p;
    for (int off = 1; off < 256; off <<= 1) {
        LV r = { -INFINITY, 1.f };
        if (t >= off) { r.re = sRe[t - off]; r.sg = sSg[t - off]; }
        __syncthreads();
        q = lcomb(r, q);
        sRe[t] = q.re; sSg[t] = q.sg;
        __syncthreads();
    }
    LV pref = { -INFINITY, 1.f };
    if (t > 0) { pref.re = sRe[t - 1]; pref.sg = sSg[t - 1]; }
    #pragma unroll
    for (int i = 0; i < 32; ++i) {
        LV f = lcomb(pref, lr[i]);
        hv[i] = f.sg * expf(la[i] + f.re);
    }
    #pragma unroll
    for (int i = 0; i < 8; ++i)
        *(float4*)&hp[t * 32 + i * 4] = *(const float4*)&hv[i * 4];
}

// ---------------------------------------------------------------------------
extern "C" void kernel_launch(void* const* d_in, const int* in_sizes, int n_in,
                              void* d_out, int out_size, void* d_ws, size_t ws_size,
                              hipStream_t stream) {
    const float* x      = (const float*)d_in[0];
    const float* conv_w = (const float*)d_in[1];
    const float* h_w    = (const float*)d_in[2];
    const float* g_w    = (const float*)d_in[3];
    float* out = (float*)d_out;
    char* ws = (char*)d_ws;

    // ws layout (97 MB): c bf16 [4][512][8192] = 32MB | Wn bf16 1MB | g f32 64MB
    unsigned short* c_ws = (unsigned short*)ws;
    unsigned short* Wn   = (unsigned short*)(ws + (size_t)32 * 1024 * 1024);
    float*          g_ws = (float*)(ws + (size_t)33 * 1024 * 1024);

    prep_kernel<<<512, 256, 0, stream>>>(h_w, g_w, Wn);
    conv_kernel<<<B_ * D_, 256, 0, stream>>>(x, conv_w, c_ws);
    gemm_kernel<<<dim3(M_ / 64, L_ / 64, B_), 256, 0, stream>>>(Wn, c_ws, out, g_ws);
    fixch1_kernel<<<dim3(L_ / 256, B_), 256, 0, stream>>>(x, conv_w, h_w, out);
    logscan_kernel<<<B_ * CH_, 256, 0, stream>>>(g_ws, out);
}

// Round 7
// 320.237 us; speedup vs baseline: 2.0479x; 1.2855x over previous
//
#include <hip/hip_runtime.h>
#include <hip/hip_bf16.h>
#include <math.h>

typedef float f32x4 __attribute__((ext_vector_type(4)));
typedef short s16x8 __attribute__((ext_vector_type(8)));
typedef short s16x16 __attribute__((ext_vector_type(16)));

#define B_  4
#define D_  512
#define L_  8192
#define CH_ 512
#define M_  1024   // interleaved (h,g) rows

__device__ __forceinline__ unsigned short f2bf(float f) {
    union { float f; unsigned u; } v; v.f = f;
    unsigned r = v.u + 0x7FFFu + ((v.u >> 16) & 1u);
    return (unsigned short)(r >> 16);
}

// ---------------------------------------------------------------------------
// Kernel 1: normalize h_w / g_w rows, interleave into Wn[1024][512] bf16.
// ---------------------------------------------------------------------------
__global__ __launch_bounds__(256)
void prep_kernel(const float* __restrict__ h_w, const float* __restrict__ g_w,
                 unsigned short* __restrict__ Wn) {
    __shared__ float red[4];
    const int ch = blockIdx.x, t = threadIdx.x;
    {
        float v0 = h_w[ch * 512 + t], v1 = h_w[ch * 512 + t + 256];
        float ss = v0 * v0 + v1 * v1;
        #pragma unroll
        for (int off = 32; off > 0; off >>= 1) ss += __shfl_down(ss, off, 64);
        if ((t & 63) == 0) red[t >> 6] = ss;
        __syncthreads();
        float tot = red[0] + red[1] + red[2] + red[3];
        float scale = 1.f / (sqrtf(tot) + 1e-4f * sqrtf(512.f));
        Wn[(size_t)(2 * ch) * 512 + t]       = f2bf(v0 * scale);
        Wn[(size_t)(2 * ch) * 512 + t + 256] = f2bf(v1 * scale);
    }
    __syncthreads();
    if (ch >= 2) {
        float v0 = g_w[(ch - 2) * 512 + t], v1 = g_w[(ch - 2) * 512 + t + 256];
        float ss = v0 * v0 + v1 * v1;
        #pragma unroll
        for (int off = 32; off > 0; off >>= 1) ss += __shfl_down(ss, off, 64);
        if ((t & 63) == 0) red[t >> 6] = ss;
        __syncthreads();
        float tot = red[0] + red[1] + red[2] + red[3];
        float scale = 1.f / (sqrtf(tot) + 1e-4f * sqrtf(512.f));
        Wn[(size_t)(2 * ch + 1) * 512 + t]       = f2bf(v0 * scale);
        Wn[(size_t)(2 * ch + 1) * 512 + t + 256] = f2bf(v1 * scale);
    } else {
        Wn[(size_t)(2 * ch + 1) * 512 + t]       = 0;
        Wn[(size_t)(2 * ch + 1) * 512 + t + 256] = 0;
    }
}

// ---------------------------------------------------------------------------
// Kernel 2: depthwise 5-tap conv, pad=2, bf16 out into C[b][d][l] (in d_out).
// ---------------------------------------------------------------------------
__global__ __launch_bounds__(256)
void conv_kernel(const float* __restrict__ x, const float* __restrict__ cw,
                 unsigned short* __restrict__ C) {
    __shared__ float xs[8200];
    const int row = blockIdx.x;          // b*512 + d
    const int d   = row & 511;
    const int t   = threadIdx.x;
    const float* xr = x + (size_t)row * L_;
    #pragma unroll
    for (int i = 0; i < 8; ++i) {
        float4 v = *(const float4*)&xr[(i * 256 + t) * 4];
        *(float4*)&xs[4 + (i * 256 + t) * 4] = v;
    }
    if (t < 4) xs[t] = 0.f;
    if (t >= 252) xs[8196 + (t - 252)] = 0.f;
    float w0 = cw[d * 5 + 0], w1 = cw[d * 5 + 1], w2 = cw[d * 5 + 2],
          w3 = cw[d * 5 + 3], w4 = cw[d * 5 + 4];
    float ss = w0 * w0 + w1 * w1 + w2 * w2 + w3 * w3 + w4 * w4;
    float scale = 1.f / (sqrtf(ss) + 1e-4f * sqrtf(5.f));
    w0 *= scale; w1 *= scale; w2 *= scale; w3 *= scale; w4 *= scale;
    __syncthreads();
    #pragma unroll
    for (int i = 0; i < 32; ++i) {
        int l = i * 256 + t;
        float acc = w0 * xs[l + 2] + w1 * xs[l + 3] + w2 * xs[l + 4]
                  + w3 * xs[l + 5] + w4 * xs[l + 6];
        C[(size_t)row * L_ + l] = f2bf(acc);
    }
}

// ---------------------------------------------------------------------------
// Kernel 2b: transpose C[b][512][8192] -> CT[(b*8192+l)][512] (bf16), 64x64
// LDS tiles.  FIX (r6): load phase now covers all 64 cols (seg*16, s16x16);
// previous version loaded only cols 0-31 -> uninitialized LDS -> NaN.
// ---------------------------------------------------------------------------
__global__ __launch_bounds__(256)
void transpose_kernel(const unsigned short* __restrict__ C,
                      unsigned short* __restrict__ CT) {
    __shared__ unsigned short tile[64 * 72];
    const int t  = threadIdx.x;
    const int l0 = blockIdx.x * 64, d0 = blockIdx.y * 64, b = blockIdx.z;
    {
        int r = t >> 2, seg = t & 3;
        s16x16 v = *(const s16x16*)&C[(size_t)(b * 512 + d0 + r) * L_ + l0 + seg * 16];
        *(s16x16*)&tile[r * 72 + seg * 16] = v;
    }
    __syncthreads();
    {
        int lr = t >> 2, seg = t & 3;
        unsigned short tmp[16];
        #pragma unroll
        for (int j = 0; j < 16; ++j) tmp[j] = tile[(seg * 16 + j) * 72 + lr];
        *(s16x16*)&CT[(size_t)(b * 8192 + l0 + lr) * 512 + d0 + seg * 16] =
            *(const s16x16*)tmp;
    }
}

// ---------------------------------------------------------------------------
// Kernel 3: bf16 MFMA GEMM, 128x128 tile, BK=32, 4 waves (64x64 each).
// A = Wn[1024][512], B = CT[32768][512] (both row-major in K).
// Fused epilogue emits log-space quantities:
//   zb  = logsig(g) + log(max(|h|,1e-6))          -> ZB (d_out)
//   enc = logsig(-g) with sign(h) packed in sign bit -> LA (ws)
//       (h>=0 -> enc = -|la| ; h<0 -> enc = +|la|)
// ch0: g=-1000, ch1: g=+1000 (overridden; ch1 later fixed by fixch1).
// ---------------------------------------------------------------------------
__global__ __launch_bounds__(256)
void gemm_kernel(const unsigned short* __restrict__ Wn,
                 const unsigned short* __restrict__ CT,
                 float* __restrict__ ZB, float* __restrict__ LA) {
    __shared__ unsigned short As[128 * 40];   // [row][k] stride 40 (2-way banks)
    __shared__ unsigned short Bs[128 * 40];
    const int t = threadIdx.x;
    const int lane = t & 63, w = t >> 6;
    // XCD-chunked swizzle: 2048 blocks = 8 XCD x 256; each XCD owns a
    // contiguous n-range (B-panel stays in its L2), A (1MB) reused everywhere.
    const int wgid = ((blockIdx.x & 7) << 8) | (blockIdx.x >> 3);
    const int mBase = (wgid & 7) * 128;
    const int nBase = (wgid >> 3) * 128;

    const int srow = t >> 2, sq = t & 3;
    const int wrow = (w >> 1) * 64, wcol = (w & 1) * 64;

    f32x4 acc[4][4];
    #pragma unroll
    for (int fr = 0; fr < 4; ++fr)
        #pragma unroll
        for (int fc = 0; fc < 4; ++fc)
            acc[fr][fc] = (f32x4){0.f, 0.f, 0.f, 0.f};

    const unsigned short* aP0 = &Wn[(size_t)(mBase + srow) * 512 + sq * 8];
    const unsigned short* aP1 = &Wn[(size_t)(mBase + 64 + srow) * 512 + sq * 8];
    const unsigned short* bP0 = &CT[(size_t)(nBase + srow) * 512 + sq * 8];
    const unsigned short* bP1 = &CT[(size_t)(nBase + 64 + srow) * 512 + sq * 8];

    s16x8 a0v = *(const s16x8*)aP0;
    s16x8 a1v = *(const s16x8*)aP1;
    s16x8 b0v = *(const s16x8*)bP0;
    s16x8 b1v = *(const s16x8*)bP1;

    unsigned short* wA0 = &As[srow * 40 + sq * 8];
    unsigned short* wA1 = &As[(64 + srow) * 40 + sq * 8];
    unsigned short* wB0 = &Bs[srow * 40 + sq * 8];
    unsigned short* wB1 = &Bs[(64 + srow) * 40 + sq * 8];

    #pragma unroll
    for (int ks = 0; ks < 16; ++ks) {
        *(s16x8*)wA0 = a0v;
        *(s16x8*)wA1 = a1v;
        *(s16x8*)wB0 = b0v;
        *(s16x8*)wB1 = b1v;
        __syncthreads();
        if (ks < 15) {
            const int k0 = (ks + 1) * 32;
            a0v = *(const s16x8*)(aP0 + k0);
            a1v = *(const s16x8*)(aP1 + k0);
            b0v = *(const s16x8*)(bP0 + k0);
            b1v = *(const s16x8*)(bP1 + k0);
        }
        s16x8 af[4], bf[4];
        #pragma unroll
        for (int f = 0; f < 4; ++f) {
            af[f] = *(const s16x8*)&As[(wrow + f * 16 + (lane & 15)) * 40 + (lane >> 4) * 8];
            bf[f] = *(const s16x8*)&Bs[(wcol + f * 16 + (lane & 15)) * 40 + (lane >> 4) * 8];
        }
        #pragma unroll
        for (int fr = 0; fr < 4; ++fr)
            #pragma unroll
            for (int fc = 0; fc < 4; ++fc)
                acc[fr][fc] = __builtin_amdgcn_mfma_f32_16x16x32_bf16(
                    af[fr], bf[fc], acc[fr][fc], 0, 0, 0);
        __syncthreads();
    }

    #pragma unroll
    for (int fr = 0; fr < 4; ++fr)
    #pragma unroll
    for (int fc = 0; fc < 4; ++fc) {
        f32x4 a = acc[fr][fc];
        const int gR0 = mBase + wrow + fr * 16 + ((lane >> 4) * 4);
        const int n   = nBase + wcol + fc * 16 + (lane & 15);
        const int bb  = n >> 13, l = n & 8191;
        #pragma unroll
        for (int p = 0; p < 2; ++p) {
            float hv = a[2 * p], gv = a[2 * p + 1];
            const int ch = (gR0 >> 1) + p;
            if (ch == 0)      gv = -1000.f;
            else if (ch == 1) gv =  1000.f;
            float l1 = log1pf(expf(-fabsf(gv)));
            float la = fminf(-gv, 0.f) - l1;         // logsig(-g) <= 0
            float ls = fminf(gv, 0.f) - l1;          // logsig(g)
            float zb = ls + logf(fmaxf(fabsf(hv), 1e-6f));
            float enc = (hv < 0.f) ? fabsf(la) : -fabsf(la);
            size_t off = ((size_t)bb * CH_ + ch) * L_ + l;
            ZB[off] = zb;
            LA[off] = enc;
        }
    }
}

// ---------------------------------------------------------------------------
// Kernel 3b: recompute h[b][1][:] in full f32 and rewrite ch1's (la, zb).
// (ch1 output = sign*exp(0.5-ULP-quantized log|h|): needs f32-exact h.)
// ---------------------------------------------------------------------------
__global__ __launch_bounds__(256)
void fixch1_kernel(const float* __restrict__ x, const float* __restrict__ cw,
                   const float* __restrict__ h_w,
                   float* __restrict__ ZB, float* __restrict__ LA) {
    __shared__ float wc[512][5];
    __shared__ float w1n[512];
    __shared__ float red[4];
    const int b = blockIdx.y;
    const int l = blockIdx.x * 256 + threadIdx.x;
    const int t = threadIdx.x;
    for (int d = t; d < 512; d += 256) {
        float a0 = cw[d * 5 + 0], a1 = cw[d * 5 + 1], a2 = cw[d * 5 + 2],
              a3 = cw[d * 5 + 3], a4 = cw[d * 5 + 4];
        float ss = a0 * a0 + a1 * a1 + a2 * a2 + a3 * a3 + a4 * a4;
        float sc = 1.f / (sqrtf(ss) + 1e-4f * sqrtf(5.f));
        wc[d][0] = a0 * sc; wc[d][1] = a1 * sc; wc[d][2] = a2 * sc;
        wc[d][3] = a3 * sc; wc[d][4] = a4 * sc;
    }
    {
        float v0 = h_w[512 + t], v1 = h_w[512 + t + 256];  // h_w row 1
        float ss = v0 * v0 + v1 * v1;
        #pragma unroll
        for (int off = 32; off > 0; off >>= 1) ss += __shfl_down(ss, off, 64);
        if ((t & 63) == 0) red[t >> 6] = ss;
        __syncthreads();
        float tot = red[0] + red[1] + red[2] + red[3];
        float sc = 1.f / (sqrtf(tot) + 1e-4f * sqrtf(512.f));
        w1n[t] = v0 * sc; w1n[t + 256] = v1 * sc;
    }
    __syncthreads();
    float acc = 0.f;
    const float* xb = x + (size_t)b * D_ * L_;
    for (int d = 0; d < 512; ++d) {
        const float* xr = xb + (size_t)d * L_;
        float x0 = (l >= 2)      ? xr[l - 2] : 0.f;
        float x1 = (l >= 1)      ? xr[l - 1] : 0.f;
        float x2 = xr[l];
        float x3 = (l + 1 < L_)  ? xr[l + 1] : 0.f;
        float x4 = (l + 2 < L_)  ? xr[l + 2] : 0.f;
        float cv = wc[d][0] * x0 + wc[d][1] * x1 + wc[d][2] * x2
                 + wc[d][3] * x3 + wc[d][4] * x4;
        acc += w1n[d] * cv;
    }
    size_t off = ((size_t)b * CH_ + 1) * L_ + l;
    LA[off] = (acc < 0.f) ? 1000.f : -1000.f;    // la=-1000, sign(h) packed
    ZB[off] = logf(fmaxf(fabsf(acc), 1e-6f));    // logsig(1000)=0
}

// ---------------------------------------------------------------------------
// Kernel 4: log-space scan from precomputed (la_enc, zb).
//   As = cumsum(-|enc|) ; z = zb - As ; signed logcumsumexp(z) ;
//   o = sg * exp(As + run.re).  Kogge-Stone shuffle scans, 2 barriers.
// ---------------------------------------------------------------------------
struct LV { float re, sg; };

__device__ __forceinline__ LV lcomb(LV a, LV b) {
    float m  = fmaxf(a.re, b.re);
    float ms = (m > -3.0e38f) ? m : 0.f;
    float s  = a.sg * expf(a.re - ms) + b.sg * expf(b.re - ms);
    LV r;
    r.re = ms + logf(fabsf(s));
    r.sg = (s < 0.f) ? -1.f : 1.f;
    return r;
}

__global__ __launch_bounds__(256)
void logscan_kernel(const float* __restrict__ LA, float* __restrict__ ZO) {
    __shared__ float wA[4];
    __shared__ float wRe[4], wSg[4];
    const int row = blockIdx.x;
    const int t = threadIdx.x;
    const int lane = t & 63, wid = t >> 6;
    const float* ep = LA + (size_t)row * L_;
    float* zp = ZO + (size_t)row * L_;

    float As[32];
    unsigned sgb = 0;
    float run = 0.f;
    #pragma unroll
    for (int i = 0; i < 8; ++i) {
        float4 e4 = *(const float4*)&ep[t * 32 + i * 4];
        float ev0 = e4.x, ev1 = e4.y, ev2 = e4.z, ev3 = e4.w;
        if (!(__float_as_uint(ev0) >> 31)) sgb |= (1u << (i * 4 + 0));
        if (!(__float_as_uint(ev1) >> 31)) sgb |= (1u << (i * 4 + 1));
        if (!(__float_as_uint(ev2) >> 31)) sgb |= (1u << (i * 4 + 2));
        if (!(__float_as_uint(ev3) >> 31)) sgb |= (1u << (i * 4 + 3));
        run -= fabsf(ev0); As[i * 4 + 0] = run;
        run -= fabsf(ev1); As[i * 4 + 1] = run;
        run -= fabsf(ev2); As[i * 4 + 2] = run;
        run -= fabsf(ev3); As[i * 4 + 3] = run;
    }
    // wave inclusive scan of per-thread sums
    float wsc = run;
    #pragma unroll
    for (int off = 1; off < 64; off <<= 1) {
        float u = __shfl_up(wsc, off, 64);
        if (lane >= off) wsc += u;
    }
    if (lane == 63) wA[wid] = wsc;
    __syncthreads();
    float pre = wsc - run;                    // exclusive within wave
    for (int j = 0; j < wid; ++j) pre += wA[j];
    #pragma unroll
    for (int i = 0; i < 32; ++i) As[i] += pre;

    // z and per-thread LV fold
    float zz[32];
    LV tot = { -INFINITY, 1.f };
    #pragma unroll
    for (int i = 0; i < 8; ++i) {
        float4 z4 = *(const float4*)&zp[t * 32 + i * 4];
        float zv0 = z4.x, zv1 = z4.y, zv2 = z4.z, zv3 = z4.w;
        #pragma unroll
        for (int j = 0; j < 4; ++j) {
            int k = i * 4 + j;
            float zvj = (j == 0) ? zv0 : (j == 1) ? zv1 : (j == 2) ? zv2 : zv3;
            zz[k] = zvj - As[k];
            LV zi = { zz[k], ((sgb >> k) & 1) ? -1.f : 1.f };
            tot = lcomb(tot, zi);
        }
    }
    // wave inclusive LV scan
    LV sc = tot;
    #pragma unroll
    for (int off = 1; off < 64; off <<= 1) {
        float ure = __shfl_up(sc.re, off, 64);
        float usg = __shfl_up(sc.sg, off, 64);
        if (lane >= off) { LV u = { ure, usg }; sc = lcomb(u, sc); }
    }
    if (lane == 63) { wRe[wid] = sc.re; wSg[wid] = sc.sg; }
    __syncthreads();
    float pr = __shfl_up(sc.re, 1, 64);
    float ps = __shfl_up(sc.sg, 1, 64);
    LV lex = { -INFINITY, 1.f };
    if (lane != 0) { lex.re = pr; lex.sg = ps; }
    LV wpre = { -INFINITY, 1.f };
    for (int j = 0; j < wid; ++j) { LV u = { wRe[j], wSg[j] }; wpre = lcomb(wpre, u); }
    LV pref = lcomb(wpre, lex);

    // final pass: fold prefix through own elements, write o
    LV run2 = pref;
    #pragma unroll
    for (int i = 0; i < 8; ++i) {
        float4 o4;
        #pragma unroll
        for (int j = 0; j < 4; ++j) {
            int k = i * 4 + j;
            LV zi = { zz[k], ((sgb >> k) & 1) ? -1.f : 1.f };
            run2 = lcomb(run2, zi);
            float ov = run2.sg * expf(As[k] + run2.re);
            if (j == 0) o4.x = ov; else if (j == 1) o4.y = ov;
            else if (j == 2) o4.z = ov; else o4.w = ov;
        }
        *(float4*)&zp[t * 32 + i * 4] = o4;
    }
}

// ---------------------------------------------------------------------------
extern "C" void kernel_launch(void* const* d_in, const int* in_sizes, int n_in,
                              void* d_out, int out_size, void* d_ws, size_t ws_size,
                              hipStream_t stream) {
    const float* x      = (const float*)d_in[0];
    const float* conv_w = (const float*)d_in[1];
    const float* h_w    = (const float*)d_in[2];
    const float* g_w    = (const float*)d_in[3];
    float* out = (float*)d_out;
    char* ws = (char*)d_ws;

    // ws layout (97 MB): CT bf16 [32768][512] = 32MB | Wn bf16 1MB | LA f32 64MB
    unsigned short* CT  = (unsigned short*)ws;
    unsigned short* Wn  = (unsigned short*)(ws + (size_t)32 * 1024 * 1024);
    float*          la  = (float*)(ws + (size_t)33 * 1024 * 1024);
    // C bf16 lives in first 32MB of d_out (dead after transpose; gemm then
    // overwrites all of d_out with zb).
    unsigned short* C   = (unsigned short*)d_out;

    prep_kernel<<<512, 256, 0, stream>>>(h_w, g_w, Wn);
    conv_kernel<<<B_ * D_, 256, 0, stream>>>(x, conv_w, C);
    transpose_kernel<<<dim3(128, 8, 4), 256, 0, stream>>>(C, CT);
    gemm_kernel<<<2048, 256, 0, stream>>>(Wn, CT, out, la);
    fixch1_kernel<<<dim3(L_ / 256, B_), 256, 0, stream>>>(x, conv_w, h_w, out, la);
    logscan_kernel<<<B_ * CH_, 256, 0, stream>>>(la, out);
}

// Round 8
// 273.364 us; speedup vs baseline: 2.3991x; 1.1715x over previous
//
#include <hip/hip_runtime.h>
#include <hip/hip_bf16.h>
#include <math.h>

typedef float f32x4 __attribute__((ext_vector_type(4)));
typedef short s16x8 __attribute__((ext_vector_type(8)));
typedef short s16x16 __attribute__((ext_vector_type(16)));

#define B_  4
#define D_  512
#define L_  8192
#define CH_ 512
#define M_  1024   // interleaved (h,g) rows

__device__ __forceinline__ unsigned short f2bf(float f) {
    union { float f; unsigned u; } v; v.f = f;
    unsigned r = v.u + 0x7FFFu + ((v.u >> 16) & 1u);
    return (unsigned short)(r >> 16);
}

// ---------------------------------------------------------------------------
// Kernel 1: normalize h_w / g_w rows, interleave into Wn[1024][512] bf16.
// ---------------------------------------------------------------------------
__global__ __launch_bounds__(256)
void prep_kernel(const float* __restrict__ h_w, const float* __restrict__ g_w,
                 unsigned short* __restrict__ Wn) {
    __shared__ float red[4];
    const int ch = blockIdx.x, t = threadIdx.x;
    {
        float v0 = h_w[ch * 512 + t], v1 = h_w[ch * 512 + t + 256];
        float ss = v0 * v0 + v1 * v1;
        #pragma unroll
        for (int off = 32; off > 0; off >>= 1) ss += __shfl_down(ss, off, 64);
        if ((t & 63) == 0) red[t >> 6] = ss;
        __syncthreads();
        float tot = red[0] + red[1] + red[2] + red[3];
        float scale = 1.f / (sqrtf(tot) + 1e-4f * sqrtf(512.f));
        Wn[(size_t)(2 * ch) * 512 + t]       = f2bf(v0 * scale);
        Wn[(size_t)(2 * ch) * 512 + t + 256] = f2bf(v1 * scale);
    }
    __syncthreads();
    if (ch >= 2) {
        float v0 = g_w[(ch - 2) * 512 + t], v1 = g_w[(ch - 2) * 512 + t + 256];
        float ss = v0 * v0 + v1 * v1;
        #pragma unroll
        for (int off = 32; off > 0; off >>= 1) ss += __shfl_down(ss, off, 64);
        if ((t & 63) == 0) red[t >> 6] = ss;
        __syncthreads();
        float tot = red[0] + red[1] + red[2] + red[3];
        float scale = 1.f / (sqrtf(tot) + 1e-4f * sqrtf(512.f));
        Wn[(size_t)(2 * ch + 1) * 512 + t]       = f2bf(v0 * scale);
        Wn[(size_t)(2 * ch + 1) * 512 + t + 256] = f2bf(v1 * scale);
    } else {
        Wn[(size_t)(2 * ch + 1) * 512 + t]       = 0;
        Wn[(size_t)(2 * ch + 1) * 512 + t + 256] = 0;
    }
}

// ---------------------------------------------------------------------------
// Kernel 2: depthwise 5-tap conv, pad=2, bf16 out into C[b][d][l] (in d_out).
// ---------------------------------------------------------------------------
__global__ __launch_bounds__(256)
void conv_kernel(const float* __restrict__ x, const float* __restrict__ cw,
                 unsigned short* __restrict__ C) {
    __shared__ float xs[8200];
    const int row = blockIdx.x;          // b*512 + d
    const int d   = row & 511;
    const int t   = threadIdx.x;
    const float* xr = x + (size_t)row * L_;
    #pragma unroll
    for (int i = 0; i < 8; ++i) {
        float4 v = *(const float4*)&xr[(i * 256 + t) * 4];
        *(float4*)&xs[4 + (i * 256 + t) * 4] = v;
    }
    if (t < 4) xs[t] = 0.f;
    if (t >= 252) xs[8196 + (t - 252)] = 0.f;
    float w0 = cw[d * 5 + 0], w1 = cw[d * 5 + 1], w2 = cw[d * 5 + 2],
          w3 = cw[d * 5 + 3], w4 = cw[d * 5 + 4];
    float ss = w0 * w0 + w1 * w1 + w2 * w2 + w3 * w3 + w4 * w4;
    float scale = 1.f / (sqrtf(ss) + 1e-4f * sqrtf(5.f));
    w0 *= scale; w1 *= scale; w2 *= scale; w3 *= scale; w4 *= scale;
    __syncthreads();
    #pragma unroll
    for (int i = 0; i < 32; ++i) {
        int l = i * 256 + t;
        float acc = w0 * xs[l + 2] + w1 * xs[l + 3] + w2 * xs[l + 4]
                  + w3 * xs[l + 5] + w4 * xs[l + 6];
        C[(size_t)row * L_ + l] = f2bf(acc);
    }
}

// ---------------------------------------------------------------------------
// Kernel 2b: transpose C[b][512][8192] -> CT[(b*8192+l)][512] (bf16), 64x64
// LDS tiles.
// ---------------------------------------------------------------------------
__global__ __launch_bounds__(256)
void transpose_kernel(const unsigned short* __restrict__ C,
                      unsigned short* __restrict__ CT) {
    __shared__ unsigned short tile[64 * 72];
    const int t  = threadIdx.x;
    const int l0 = blockIdx.x * 64, d0 = blockIdx.y * 64, b = blockIdx.z;
    {
        int r = t >> 2, seg = t & 3;
        s16x16 v = *(const s16x16*)&C[(size_t)(b * 512 + d0 + r) * L_ + l0 + seg * 16];
        *(s16x16*)&tile[r * 72 + seg * 16] = v;
    }
    __syncthreads();
    {
        int lr = t >> 2, seg = t & 3;
        unsigned short tmp[16];
        #pragma unroll
        for (int j = 0; j < 16; ++j) tmp[j] = tile[(seg * 16 + j) * 72 + lr];
        *(s16x16*)&CT[(size_t)(b * 8192 + l0 + lr) * 512 + d0 + seg * 16] =
            *(const s16x16*)tmp;
    }
}

// ---------------------------------------------------------------------------
// Kernel 3: bf16 MFMA GEMM, 128x128 tile, BK=32, 4 waves (64x64 each).
// Fused epilogue emits log-space quantities (zb -> d_out, enc(la,sign) -> ws).
// ---------------------------------------------------------------------------
__global__ __launch_bounds__(256)
void gemm_kernel(const unsigned short* __restrict__ Wn,
                 const unsigned short* __restrict__ CT,
                 float* __restrict__ ZB, float* __restrict__ LA) {
    __shared__ unsigned short As[128 * 40];   // [row][k] stride 40 (2-way banks)
    __shared__ unsigned short Bs[128 * 40];
    const int t = threadIdx.x;
    const int lane = t & 63, w = t >> 6;
    const int wgid = ((blockIdx.x & 7) << 8) | (blockIdx.x >> 3);
    const int mBase = (wgid & 7) * 128;
    const int nBase = (wgid >> 3) * 128;

    const int srow = t >> 2, sq = t & 3;
    const int wrow = (w >> 1) * 64, wcol = (w & 1) * 64;

    f32x4 acc[4][4];
    #pragma unroll
    for (int fr = 0; fr < 4; ++fr)
        #pragma unroll
        for (int fc = 0; fc < 4; ++fc)
            acc[fr][fc] = (f32x4){0.f, 0.f, 0.f, 0.f};

    const unsigned short* aP0 = &Wn[(size_t)(mBase + srow) * 512 + sq * 8];
    const unsigned short* aP1 = &Wn[(size_t)(mBase + 64 + srow) * 512 + sq * 8];
    const unsigned short* bP0 = &CT[(size_t)(nBase + srow) * 512 + sq * 8];
    const unsigned short* bP1 = &CT[(size_t)(nBase + 64 + srow) * 512 + sq * 8];

    s16x8 a0v = *(const s16x8*)aP0;
    s16x8 a1v = *(const s16x8*)aP1;
    s16x8 b0v = *(const s16x8*)bP0;
    s16x8 b1v = *(const s16x8*)bP1;

    unsigned short* wA0 = &As[srow * 40 + sq * 8];
    unsigned short* wA1 = &As[(64 + srow) * 40 + sq * 8];
    unsigned short* wB0 = &Bs[srow * 40 + sq * 8];
    unsigned short* wB1 = &Bs[(64 + srow) * 40 + sq * 8];

    #pragma unroll
    for (int ks = 0; ks < 16; ++ks) {
        *(s16x8*)wA0 = a0v;
        *(s16x8*)wA1 = a1v;
        *(s16x8*)wB0 = b0v;
        *(s16x8*)wB1 = b1v;
        __syncthreads();
        if (ks < 15) {
            const int k0 = (ks + 1) * 32;
            a0v = *(const s16x8*)(aP0 + k0);
            a1v = *(const s16x8*)(aP1 + k0);
            b0v = *(const s16x8*)(bP0 + k0);
            b1v = *(const s16x8*)(bP1 + k0);
        }
        s16x8 af[4], bf[4];
        #pragma unroll
        for (int f = 0; f < 4; ++f) {
            af[f] = *(const s16x8*)&As[(wrow + f * 16 + (lane & 15)) * 40 + (lane >> 4) * 8];
            bf[f] = *(const s16x8*)&Bs[(wcol + f * 16 + (lane & 15)) * 40 + (lane >> 4) * 8];
        }
        #pragma unroll
        for (int fr = 0; fr < 4; ++fr)
            #pragma unroll
            for (int fc = 0; fc < 4; ++fc)
                acc[fr][fc] = __builtin_amdgcn_mfma_f32_16x16x32_bf16(
                    af[fr], bf[fc], acc[fr][fc], 0, 0, 0);
        __syncthreads();
    }

    #pragma unroll
    for (int fr = 0; fr < 4; ++fr)
    #pragma unroll
    for (int fc = 0; fc < 4; ++fc) {
        f32x4 a = acc[fr][fc];
        const int gR0 = mBase + wrow + fr * 16 + ((lane >> 4) * 4);
        const int n   = nBase + wcol + fc * 16 + (lane & 15);
        const int bb  = n >> 13, l = n & 8191;
        #pragma unroll
        for (int p = 0; p < 2; ++p) {
            float hv = a[2 * p], gv = a[2 * p + 1];
            const int ch = (gR0 >> 1) + p;
            if (ch == 0)      gv = -1000.f;
            else if (ch == 1) gv =  1000.f;
            float l1 = log1pf(expf(-fabsf(gv)));
            float la = fminf(-gv, 0.f) - l1;         // logsig(-g) <= 0
            float ls = fminf(gv, 0.f) - l1;          // logsig(g)
            float zb = ls + logf(fmaxf(fabsf(hv), 1e-6f));
            float enc = (hv < 0.f) ? fabsf(la) : -fabsf(la);
            size_t off = ((size_t)bb * CH_ + ch) * L_ + l;
            ZB[off] = zb;
            LA[off] = enc;
        }
    }
}

// ---------------------------------------------------------------------------
// Kernel 3b: recompute h[b][1][:] in full f32, rewrite ch1's (la, zb).
// R7 FIX: d-loop unrolled x8 — 40 independent loads issued per group, then
// the acc fma-fold runs in the IDENTICAL sequential d-order (fl() order
// preserved; ch1's 0.5-ULP log-quantization stays on the same grid).
// Was 133 us: 1 serial HBM latency per d-iteration at 5% occupancy.
// ---------------------------------------------------------------------------
__global__ __launch_bounds__(256)
void fixch1_kernel(const float* __restrict__ x, const float* __restrict__ cw,
                   const float* __restrict__ h_w,
                   float* __restrict__ ZB, float* __restrict__ LA) {
    __shared__ float wc[512][5];
    __shared__ float w1n[512];
    __shared__ float red[4];
    const int b = blockIdx.y;
    const int l = blockIdx.x * 256 + threadIdx.x;
    const int t = threadIdx.x;
    for (int d = t; d < 512; d += 256) {
        float a0 = cw[d * 5 + 0], a1 = cw[d * 5 + 1], a2 = cw[d * 5 + 2],
              a3 = cw[d * 5 + 3], a4 = cw[d * 5 + 4];
        float ss = a0 * a0 + a1 * a1 + a2 * a2 + a3 * a3 + a4 * a4;
        float sc = 1.f / (sqrtf(ss) + 1e-4f * sqrtf(5.f));
        wc[d][0] = a0 * sc; wc[d][1] = a1 * sc; wc[d][2] = a2 * sc;
        wc[d][3] = a3 * sc; wc[d][4] = a4 * sc;
    }
    {
        float v0 = h_w[512 + t], v1 = h_w[512 + t + 256];  // h_w row 1
        float ss = v0 * v0 + v1 * v1;
        #pragma unroll
        for (int off = 32; off > 0; off >>= 1) ss += __shfl_down(ss, off, 64);
        if ((t & 63) == 0) red[t >> 6] = ss;
        __syncthreads();
        float tot = red[0] + red[1] + red[2] + red[3];
        float sc = 1.f / (sqrtf(tot) + 1e-4f * sqrtf(512.f));
        w1n[t] = v0 * sc; w1n[t + 256] = v1 * sc;
    }
    __syncthreads();
    const float* xb = x + (size_t)b * D_ * L_;
    const bool lo2 = (l >= 2), lo1 = (l >= 1);
    const bool hi1 = (l + 1 < L_), hi2 = (l + 2 < L_);
    float acc = 0.f;
    for (int d0 = 0; d0 < 512; d0 += 8) {
        float cv[8];
        #pragma unroll
        for (int u = 0; u < 8; ++u) {
            const float* xr = xb + (size_t)(d0 + u) * L_;
            float x0 = lo2 ? xr[l - 2] : 0.f;
            float x1 = lo1 ? xr[l - 1] : 0.f;
            float x2 = xr[l];
            float x3 = hi1 ? xr[l + 1] : 0.f;
            float x4 = hi2 ? xr[l + 2] : 0.f;
            cv[u] = wc[d0 + u][0] * x0 + wc[d0 + u][1] * x1 + wc[d0 + u][2] * x2
                  + wc[d0 + u][3] * x3 + wc[d0 + u][4] * x4;
        }
        #pragma unroll
        for (int u = 0; u < 8; ++u) acc += w1n[d0 + u] * cv[u];
    }
    size_t off = ((size_t)b * CH_ + 1) * L_ + l;
    LA[off] = (acc < 0.f) ? 1000.f : -1000.f;    // la=-1000, sign(h) packed
    ZB[off] = logf(fmaxf(fabsf(acc), 1e-6f));    // logsig(1000)=0
}

// ---------------------------------------------------------------------------
// Kernel 4: log-space scan from precomputed (la_enc, zb).
// ---------------------------------------------------------------------------
struct LV { float re, sg; };

__device__ __forceinline__ LV lcomb(LV a, LV b) {
    float m  = fmaxf(a.re, b.re);
    float ms = (m > -3.0e38f) ? m : 0.f;
    float s  = a.sg * expf(a.re - ms) + b.sg * expf(b.re - ms);
    LV r;
    r.re = ms + logf(fabsf(s));
    r.sg = (s < 0.f) ? -1.f : 1.f;
    return r;
}

__global__ __launch_bounds__(256)
void logscan_kernel(const float* __restrict__ LA, float* __restrict__ ZO) {
    __shared__ float wA[4];
    __shared__ float wRe[4], wSg[4];
    const int row = blockIdx.x;
    const int t = threadIdx.x;
    const int lane = t & 63, wid = t >> 6;
    const float* ep = LA + (size_t)row * L_;
    float* zp = ZO + (size_t)row * L_;

    float As[32];
    unsigned sgb = 0;
    float run = 0.f;
    #pragma unroll
    for (int i = 0; i < 8; ++i) {
        float4 e4 = *(const float4*)&ep[t * 32 + i * 4];
        float ev0 = e4.x, ev1 = e4.y, ev2 = e4.z, ev3 = e4.w;
        if (!(__float_as_uint(ev0) >> 31)) sgb |= (1u << (i * 4 + 0));
        if (!(__float_as_uint(ev1) >> 31)) sgb |= (1u << (i * 4 + 1));
        if (!(__float_as_uint(ev2) >> 31)) sgb |= (1u << (i * 4 + 2));
        if (!(__float_as_uint(ev3) >> 31)) sgb |= (1u << (i * 4 + 3));
        run -= fabsf(ev0); As[i * 4 + 0] = run;
        run -= fabsf(ev1); As[i * 4 + 1] = run;
        run -= fabsf(ev2); As[i * 4 + 2] = run;
        run -= fabsf(ev3); As[i * 4 + 3] = run;
    }
    float wsc = run;
    #pragma unroll
    for (int off = 1; off < 64; off <<= 1) {
        float u = __shfl_up(wsc, off, 64);
        if (lane >= off) wsc += u;
    }
    if (lane == 63) wA[wid] = wsc;
    __syncthreads();
    float pre = wsc - run;
    for (int j = 0; j < wid; ++j) pre += wA[j];
    #pragma unroll
    for (int i = 0; i < 32; ++i) As[i] += pre;

    float zz[32];
    LV tot = { -INFINITY, 1.f };
    #pragma unroll
    for (int i = 0; i < 8; ++i) {
        float4 z4 = *(const float4*)&zp[t * 32 + i * 4];
        float zv0 = z4.x, zv1 = z4.y, zv2 = z4.z, zv3 = z4.w;
        #pragma unroll
        for (int j = 0; j < 4; ++j) {
            int k = i * 4 + j;
            float zvj = (j == 0) ? zv0 : (j == 1) ? zv1 : (j == 2) ? zv2 : zv3;
            zz[k] = zvj - As[k];
            LV zi = { zz[k], ((sgb >> k) & 1) ? -1.f : 1.f };
            tot = lcomb(tot, zi);
        }
    }
    LV sc = tot;
    #pragma unroll
    for (int off = 1; off < 64; off <<= 1) {
        float ure = __shfl_up(sc.re, off, 64);
        float usg = __shfl_up(sc.sg, off, 64);
        if (lane >= off) { LV u = { ure, usg }; sc = lcomb(u, sc); }
    }
    if (lane == 63) { wRe[wid] = sc.re; wSg[wid] = sc.sg; }
    __syncthreads();
    float pr = __shfl_up(sc.re, 1, 64);
    float ps = __shfl_up(sc.sg, 1, 64);
    LV lex = { -INFINITY, 1.f };
    if (lane != 0) { lex.re = pr; lex.sg = ps; }
    LV wpre = { -INFINITY, 1.f };
    for (int j = 0; j < wid; ++j) { LV u = { wRe[j], wSg[j] }; wpre = lcomb(wpre, u); }
    LV pref = lcomb(wpre, lex);

    LV run2 = pref;
    #pragma unroll
    for (int i = 0; i < 8; ++i) {
        float4 o4;
        #pragma unroll
        for (int j = 0; j < 4; ++j) {
            int k = i * 4 + j;
            LV zi = { zz[k], ((sgb >> k) & 1) ? -1.f : 1.f };
            run2 = lcomb(run2, zi);
            float ov = run2.sg * expf(As[k] + run2.re);
            if (j == 0) o4.x = ov; else if (j == 1) o4.y = ov;
            else if (j == 2) o4.z = ov; else o4.w = ov;
        }
        *(float4*)&zp[t * 32 + i * 4] = o4;
    }
}

// ---------------------------------------------------------------------------
extern "C" void kernel_launch(void* const* d_in, const int* in_sizes, int n_in,
                              void* d_out, int out_size, void* d_ws, size_t ws_size,
                              hipStream_t stream) {
    const float* x      = (const float*)d_in[0];
    const float* conv_w = (const float*)d_in[1];
    const float* h_w    = (const float*)d_in[2];
    const float* g_w    = (const float*)d_in[3];
    float* out = (float*)d_out;
    char* ws = (char*)d_ws;

    // ws layout (97 MB): CT bf16 [32768][512] = 32MB | Wn bf16 1MB | LA f32 64MB
    unsigned short* CT  = (unsigned short*)ws;
    unsigned short* Wn  = (unsigned short*)(ws + (size_t)32 * 1024 * 1024);
    float*          la  = (float*)(ws + (size_t)33 * 1024 * 1024);
    unsigned short* C   = (unsigned short*)d_out;

    prep_kernel<<<512, 256, 0, stream>>>(h_w, g_w, Wn);
    conv_kernel<<<B_ * D_, 256, 0, stream>>>(x, conv_w, C);
    transpose_kernel<<<dim3(128, 8, 4), 256, 0, stream>>>(C, CT);
    gemm_kernel<<<2048, 256, 0, stream>>>(Wn, CT, out, la);
    fixch1_kernel<<<dim3(L_ / 256, B_), 256, 0, stream>>>(x, conv_w, h_w, out, la);
    logscan_kernel<<<B_ * CH_, 256, 0, stream>>>(la, out);
}

// Round 9
// 229.459 us; speedup vs baseline: 2.8581x; 1.1913x over previous
//
#include <hip/hip_runtime.h>
#include <hip/hip_bf16.h>
#include <math.h>

typedef float f32x4 __attribute__((ext_vector_type(4)));
typedef short s16x8 __attribute__((ext_vector_type(8)));
typedef short s16x16 __attribute__((ext_vector_type(16)));

#define B_  4
#define D_  512
#define L_  8192
#define CH_ 512
#define M_  1024   // interleaved (h,g) rows

__device__ __forceinline__ unsigned short f2bf(float f) {
    union { float f; unsigned u; } v; v.f = f;
    unsigned r = v.u + 0x7FFFu + ((v.u >> 16) & 1u);
    return (unsigned short)(r >> 16);
}

// ---------------------------------------------------------------------------
// Kernel 1: normalize h_w / g_w rows, interleave into Wn[1024][512] bf16.
// ---------------------------------------------------------------------------
__global__ __launch_bounds__(256)
void prep_kernel(const float* __restrict__ h_w, const float* __restrict__ g_w,
                 unsigned short* __restrict__ Wn) {
    __shared__ float red[4];
    const int ch = blockIdx.x, t = threadIdx.x;
    {
        float v0 = h_w[ch * 512 + t], v1 = h_w[ch * 512 + t + 256];
        float ss = v0 * v0 + v1 * v1;
        #pragma unroll
        for (int off = 32; off > 0; off >>= 1) ss += __shfl_down(ss, off, 64);
        if ((t & 63) == 0) red[t >> 6] = ss;
        __syncthreads();
        float tot = red[0] + red[1] + red[2] + red[3];
        float scale = 1.f / (sqrtf(tot) + 1e-4f * sqrtf(512.f));
        Wn[(size_t)(2 * ch) * 512 + t]       = f2bf(v0 * scale);
        Wn[(size_t)(2 * ch) * 512 + t + 256] = f2bf(v1 * scale);
    }
    __syncthreads();
    if (ch >= 2) {
        float v0 = g_w[(ch - 2) * 512 + t], v1 = g_w[(ch - 2) * 512 + t + 256];
        float ss = v0 * v0 + v1 * v1;
        #pragma unroll
        for (int off = 32; off > 0; off >>= 1) ss += __shfl_down(ss, off, 64);
        if ((t & 63) == 0) red[t >> 6] = ss;
        __syncthreads();
        float tot = red[0] + red[1] + red[2] + red[3];
        float scale = 1.f / (sqrtf(tot) + 1e-4f * sqrtf(512.f));
        Wn[(size_t)(2 * ch + 1) * 512 + t]       = f2bf(v0 * scale);
        Wn[(size_t)(2 * ch + 1) * 512 + t + 256] = f2bf(v1 * scale);
    } else {
        Wn[(size_t)(2 * ch + 1) * 512 + t]       = 0;
        Wn[(size_t)(2 * ch + 1) * 512 + t + 256] = 0;
    }
}

// ---------------------------------------------------------------------------
// Kernel 2: depthwise 5-tap conv, pad=2, bf16 out into C[b][d][l] (in d_out).
// ---------------------------------------------------------------------------
__global__ __launch_bounds__(256)
void conv_kernel(const float* __restrict__ x, const float* __restrict__ cw,
                 unsigned short* __restrict__ C) {
    __shared__ float xs[8200];
    const int row = blockIdx.x;          // b*512 + d
    const int d   = row & 511;
    const int t   = threadIdx.x;
    const float* xr = x + (size_t)row * L_;
    #pragma unroll
    for (int i = 0; i < 8; ++i) {
        float4 v = *(const float4*)&xr[(i * 256 + t) * 4];
        *(float4*)&xs[4 + (i * 256 + t) * 4] = v;
    }
    if (t < 4) xs[t] = 0.f;
    if (t >= 252) xs[8196 + (t - 252)] = 0.f;
    float w0 = cw[d * 5 + 0], w1 = cw[d * 5 + 1], w2 = cw[d * 5 + 2],
          w3 = cw[d * 5 + 3], w4 = cw[d * 5 + 4];
    float ss = w0 * w0 + w1 * w1 + w2 * w2 + w3 * w3 + w4 * w4;
    float scale = 1.f / (sqrtf(ss) + 1e-4f * sqrtf(5.f));
    w0 *= scale; w1 *= scale; w2 *= scale; w3 *= scale; w4 *= scale;
    __syncthreads();
    #pragma unroll
    for (int i = 0; i < 32; ++i) {
        int l = i * 256 + t;
        float acc = w0 * xs[l + 2] + w1 * xs[l + 3] + w2 * xs[l + 4]
                  + w3 * xs[l + 5] + w4 * xs[l + 6];
        C[(size_t)row * L_ + l] = f2bf(acc);
    }
}

// ---------------------------------------------------------------------------
// Kernel 2b: transpose C[b][512][8192] -> CT[(b*8192+l)][512] (bf16).
// ---------------------------------------------------------------------------
__global__ __launch_bounds__(256)
void transpose_kernel(const unsigned short* __restrict__ C,
                      unsigned short* __restrict__ CT) {
    __shared__ unsigned short tile[64 * 72];
    const int t  = threadIdx.x;
    const int l0 = blockIdx.x * 64, d0 = blockIdx.y * 64, b = blockIdx.z;
    {
        int r = t >> 2, seg = t & 3;
        s16x16 v = *(const s16x16*)&C[(size_t)(b * 512 + d0 + r) * L_ + l0 + seg * 16];
        *(s16x16*)&tile[r * 72 + seg * 16] = v;
    }
    __syncthreads();
    {
        int lr = t >> 2, seg = t & 3;
        unsigned short tmp[16];
        #pragma unroll
        for (int j = 0; j < 16; ++j) tmp[j] = tile[(seg * 16 + j) * 72 + lr];
        *(s16x16*)&CT[(size_t)(b * 8192 + l0 + lr) * 512 + d0 + seg * 16] =
            *(const s16x16*)tmp;
    }
}

// ---------------------------------------------------------------------------
// Kernel 3: bf16 MFMA GEMM, 128x128 tile, BK=32, 4 waves (64x64 each).
// R8: epilogue transcendentals -> hardware (__expf/__logf).  Was VALU-bound:
// VALUBusy 66% vs MfmaUtil 13% — software expf/log1pf/logf ~2.5K VALU inst
// per thread vs ~1.3K MFMA cycles.  Generic-channel error budget ~0.02 vs
// ~1e-6 intrinsic error; ch1 precision path lives in fixch1 (software logf).
// ---------------------------------------------------------------------------
__global__ __launch_bounds__(256)
void gemm_kernel(const unsigned short* __restrict__ Wn,
                 const unsigned short* __restrict__ CT,
                 float* __restrict__ ZB, float* __restrict__ LA) {
    __shared__ unsigned short As[128 * 40];   // [row][k] stride 40 (2-way banks)
    __shared__ unsigned short Bs[128 * 40];
    const int t = threadIdx.x;
    const int lane = t & 63, w = t >> 6;
    const int wgid = ((blockIdx.x & 7) << 8) | (blockIdx.x >> 3);
    const int mBase = (wgid & 7) * 128;
    const int nBase = (wgid >> 3) * 128;

    const int srow = t >> 2, sq = t & 3;
    const int wrow = (w >> 1) * 64, wcol = (w & 1) * 64;

    f32x4 acc[4][4];
    #pragma unroll
    for (int fr = 0; fr < 4; ++fr)
        #pragma unroll
        for (int fc = 0; fc < 4; ++fc)
            acc[fr][fc] = (f32x4){0.f, 0.f, 0.f, 0.f};

    const unsigned short* aP0 = &Wn[(size_t)(mBase + srow) * 512 + sq * 8];
    const unsigned short* aP1 = &Wn[(size_t)(mBase + 64 + srow) * 512 + sq * 8];
    const unsigned short* bP0 = &CT[(size_t)(nBase + srow) * 512 + sq * 8];
    const unsigned short* bP1 = &CT[(size_t)(nBase + 64 + srow) * 512 + sq * 8];

    s16x8 a0v = *(const s16x8*)aP0;
    s16x8 a1v = *(const s16x8*)aP1;
    s16x8 b0v = *(const s16x8*)bP0;
    s16x8 b1v = *(const s16x8*)bP1;

    unsigned short* wA0 = &As[srow * 40 + sq * 8];
    unsigned short* wA1 = &As[(64 + srow) * 40 + sq * 8];
    unsigned short* wB0 = &Bs[srow * 40 + sq * 8];
    unsigned short* wB1 = &Bs[(64 + srow) * 40 + sq * 8];

    #pragma unroll
    for (int ks = 0; ks < 16; ++ks) {
        *(s16x8*)wA0 = a0v;
        *(s16x8*)wA1 = a1v;
        *(s16x8*)wB0 = b0v;
        *(s16x8*)wB1 = b1v;
        __syncthreads();
        if (ks < 15) {
            const int k0 = (ks + 1) * 32;
            a0v = *(const s16x8*)(aP0 + k0);
            a1v = *(const s16x8*)(aP1 + k0);
            b0v = *(const s16x8*)(bP0 + k0);
            b1v = *(const s16x8*)(bP1 + k0);
        }
        s16x8 af[4], bf[4];
        #pragma unroll
        for (int f = 0; f < 4; ++f) {
            af[f] = *(const s16x8*)&As[(wrow + f * 16 + (lane & 15)) * 40 + (lane >> 4) * 8];
            bf[f] = *(const s16x8*)&Bs[(wcol + f * 16 + (lane & 15)) * 40 + (lane >> 4) * 8];
        }
        #pragma unroll
        for (int fr = 0; fr < 4; ++fr)
            #pragma unroll
            for (int fc = 0; fc < 4; ++fc)
                acc[fr][fc] = __builtin_amdgcn_mfma_f32_16x16x32_bf16(
                    af[fr], bf[fc], acc[fr][fc], 0, 0, 0);
        __syncthreads();
    }

    #pragma unroll
    for (int fr = 0; fr < 4; ++fr)
    #pragma unroll
    for (int fc = 0; fc < 4; ++fc) {
        f32x4 a = acc[fr][fc];
        const int gR0 = mBase + wrow + fr * 16 + ((lane >> 4) * 4);
        const int n   = nBase + wcol + fc * 16 + (lane & 15);
        const int bb  = n >> 13, l = n & 8191;
        #pragma unroll
        for (int p = 0; p < 2; ++p) {
            float hv = a[2 * p], gv = a[2 * p + 1];
            const int ch = (gR0 >> 1) + p;
            if (ch == 0)      gv = -1000.f;
            else if (ch == 1) gv =  1000.f;
            float e  = __expf(-fabsf(gv));
            float l1 = __logf(1.f + e);                 // log1p(exp(-|g|))
            float la = fminf(-gv, 0.f) - l1;            // logsig(-g) <= 0
            float ls = fminf(gv, 0.f) - l1;             // logsig(g)
            float zb = ls + __logf(fmaxf(fabsf(hv), 1e-6f));
            float enc = (hv < 0.f) ? fabsf(la) : -fabsf(la);
            size_t off = ((size_t)bb * CH_ + ch) * L_ + l;
            ZB[off] = zb;
            LA[off] = enc;
        }
    }
}

// ---------------------------------------------------------------------------
// Kernel 3b: recompute h[b][1][:] in full f32, rewrite ch1's (la, zb).
// Keeps SOFTWARE logf: ch1's output is exp(0.5-ULP-quantized log|h|).
// ---------------------------------------------------------------------------
__global__ __launch_bounds__(256)
void fixch1_kernel(const float* __restrict__ x, const float* __restrict__ cw,
                   const float* __restrict__ h_w,
                   float* __restrict__ ZB, float* __restrict__ LA) {
    __shared__ float wc[512][5];
    __shared__ float w1n[512];
    __shared__ float red[4];
    const int b = blockIdx.y;
    const int l = blockIdx.x * 256 + threadIdx.x;
    const int t = threadIdx.x;
    for (int d = t; d < 512; d += 256) {
        float a0 = cw[d * 5 + 0], a1 = cw[d * 5 + 1], a2 = cw[d * 5 + 2],
              a3 = cw[d * 5 + 3], a4 = cw[d * 5 + 4];
        float ss = a0 * a0 + a1 * a1 + a2 * a2 + a3 * a3 + a4 * a4;
        float sc = 1.f / (sqrtf(ss) + 1e-4f * sqrtf(5.f));
        wc[d][0] = a0 * sc; wc[d][1] = a1 * sc; wc[d][2] = a2 * sc;
        wc[d][3] = a3 * sc; wc[d][4] = a4 * sc;
    }
    {
        float v0 = h_w[512 + t], v1 = h_w[512 + t + 256];  // h_w row 1
        float ss = v0 * v0 + v1 * v1;
        #pragma unroll
        for (int off = 32; off > 0; off >>= 1) ss += __shfl_down(ss, off, 64);
        if ((t & 63) == 0) red[t >> 6] = ss;
        __syncthreads();
        float tot = red[0] + red[1] + red[2] + red[3];
        float sc = 1.f / (sqrtf(tot) + 1e-4f * sqrtf(512.f));
        w1n[t] = v0 * sc; w1n[t + 256] = v1 * sc;
    }
    __syncthreads();
    const float* xb = x + (size_t)b * D_ * L_;
    const bool lo2 = (l >= 2), lo1 = (l >= 1);
    const bool hi1 = (l + 1 < L_), hi2 = (l + 2 < L_);
    float acc = 0.f;
    for (int d0 = 0; d0 < 512; d0 += 8) {
        float cv[8];
        #pragma unroll
        for (int u = 0; u < 8; ++u) {
            const float* xr = xb + (size_t)(d0 + u) * L_;
            float x0 = lo2 ? xr[l - 2] : 0.f;
            float x1 = lo1 ? xr[l - 1] : 0.f;
            float x2 = xr[l];
            float x3 = hi1 ? xr[l + 1] : 0.f;
            float x4 = hi2 ? xr[l + 2] : 0.f;
            cv[u] = wc[d0 + u][0] * x0 + wc[d0 + u][1] * x1 + wc[d0 + u][2] * x2
                  + wc[d0 + u][3] * x3 + wc[d0 + u][4] * x4;
        }
        #pragma unroll
        for (int u = 0; u < 8; ++u) acc += w1n[d0 + u] * cv[u];
    }
    size_t off = ((size_t)b * CH_ + 1) * L_ + l;
    LA[off] = (acc < 0.f) ? 1000.f : -1000.f;    // la=-1000, sign(h) packed
    ZB[off] = logf(fmaxf(fabsf(acc), 1e-6f));    // logsig(1000)=0
}

// ---------------------------------------------------------------------------
// Kernel 4: log-space scan from precomputed (la_enc, zb).
// R8: hardware __expf/__logf in lcomb (ch1 algebra stays exact: __expf(-1000)
// =0, __logf(1)=0; generic channels' 1e-7/step noise -> ~1e-3 log accum,
// well under the 0.02 budget).
// ---------------------------------------------------------------------------
struct LV { float re, sg; };

__device__ __forceinline__ LV lcomb(LV a, LV b) {
    float m  = fmaxf(a.re, b.re);
    float ms = (m > -3.0e38f) ? m : 0.f;
    float s  = a.sg * __expf(a.re - ms) + b.sg * __expf(b.re - ms);
    LV r;
    r.re = ms + __logf(fabsf(s));
    r.sg = (s < 0.f) ? -1.f : 1.f;
    return r;
}

__global__ __launch_bounds__(256)
void logscan_kernel(const float* __restrict__ LA, float* __restrict__ ZO) {
    __shared__ float wA[4];
    __shared__ float wRe[4], wSg[4];
    const int row = blockIdx.x;
    const int t = threadIdx.x;
    const int lane = t & 63, wid = t >> 6;
    const float* ep = LA + (size_t)row * L_;
    float* zp = ZO + (size_t)row * L_;

    float As[32];
    unsigned sgb = 0;
    float run = 0.f;
    #pragma unroll
    for (int i = 0; i < 8; ++i) {
        float4 e4 = *(const float4*)&ep[t * 32 + i * 4];
        float ev0 = e4.x, ev1 = e4.y, ev2 = e4.z, ev3 = e4.w;
        if (!(__float_as_uint(ev0) >> 31)) sgb |= (1u << (i * 4 + 0));
        if (!(__float_as_uint(ev1) >> 31)) sgb |= (1u << (i * 4 + 1));
        if (!(__float_as_uint(ev2) >> 31)) sgb |= (1u << (i * 4 + 2));
        if (!(__float_as_uint(ev3) >> 31)) sgb |= (1u << (i * 4 + 3));
        run -= fabsf(ev0); As[i * 4 + 0] = run;
        run -= fabsf(ev1); As[i * 4 + 1] = run;
        run -= fabsf(ev2); As[i * 4 + 2] = run;
        run -= fabsf(ev3); As[i * 4 + 3] = run;
    }
    float wsc = run;
    #pragma unroll
    for (int off = 1; off < 64; off <<= 1) {
        float u = __shfl_up(wsc, off, 64);
        if (lane >= off) wsc += u;
    }
    if (lane == 63) wA[wid] = wsc;
    __syncthreads();
    float pre = wsc - run;
    for (int j = 0; j < wid; ++j) pre += wA[j];
    #pragma unroll
    for (int i = 0; i < 32; ++i) As[i] += pre;

    float zz[32];
    LV tot = { -INFINITY, 1.f };
    #pragma unroll
    for (int i = 0; i < 8; ++i) {
        float4 z4 = *(const float4*)&zp[t * 32 + i * 4];
        float zv0 = z4.x, zv1 = z4.y, zv2 = z4.z, zv3 = z4.w;
        #pragma unroll
        for (int j = 0; j < 4; ++j) {
            int k = i * 4 + j;
            float zvj = (j == 0) ? zv0 : (j == 1) ? zv1 : (j == 2) ? zv2 : zv3;
            zz[k] = zvj - As[k];
            LV zi = { zz[k], ((sgb >> k) & 1) ? -1.f : 1.f };
            tot = lcomb(tot, zi);
        }
    }
    LV sc = tot;
    #pragma unroll
    for (int off = 1; off < 64; off <<= 1) {
        float ure = __shfl_up(sc.re, off, 64);
        float usg = __shfl_up(sc.sg, off, 64);
        if (lane >= off) { LV u = { ure, usg }; sc = lcomb(u, sc); }
    }
    if (lane == 63) { wRe[wid] = sc.re; wSg[wid] = sc.sg; }
    __syncthreads();
    float pr = __shfl_up(sc.re, 1, 64);
    float ps = __shfl_up(sc.sg, 1, 64);
    LV lex = { -INFINITY, 1.f };
    if (lane != 0) { lex.re = pr; lex.sg = ps; }
    LV wpre = { -INFINITY, 1.f };
    for (int j = 0; j < wid; ++j) { LV u = { wRe[j], wSg[j] }; wpre = lcomb(wpre, u); }
    LV pref = lcomb(wpre, lex);

    LV run2 = pref;
    #pragma unroll
    for (int i = 0; i < 8; ++i) {
        float4 o4;
        #pragma unroll
        for (int j = 0; j < 4; ++j) {
            int k = i * 4 + j;
            LV zi = { zz[k], ((sgb >> k) & 1) ? -1.f : 1.f };
            run2 = lcomb(run2, zi);
            float ov = run2.sg * __expf(As[k] + run2.re);
            if (j == 0) o4.x = ov; else if (j == 1) o4.y = ov;
            else if (j == 2) o4.z = ov; else o4.w = ov;
        }
        *(float4*)&zp[t * 32 + i * 4] = o4;
    }
}

// ---------------------------------------------------------------------------
extern "C" void kernel_launch(void* const* d_in, const int* in_sizes, int n_in,
                              void* d_out, int out_size, void* d_ws, size_t ws_size,
                              hipStream_t stream) {
    const float* x      = (const float*)d_in[0];
    const float* conv_w = (const float*)d_in[1];
    const float* h_w    = (const float*)d_in[2];
    const float* g_w    = (const float*)d_in[3];
    float* out = (float*)d_out;
    char* ws = (char*)d_ws;

    // ws layout (97 MB): CT bf16 [32768][512] = 32MB | Wn bf16 1MB | LA f32 64MB
    unsigned short* CT  = (unsigned short*)ws;
    unsigned short* Wn  = (unsigned short*)(ws + (size_t)32 * 1024 * 1024);
    float*          la  = (float*)(ws + (size_t)33 * 1024 * 1024);
    unsigned short* C   = (unsigned short*)d_out;

    prep_kernel<<<512, 256, 0, stream>>>(h_w, g_w, Wn);
    conv_kernel<<<B_ * D_, 256, 0, stream>>>(x, conv_w, C);
    transpose_kernel<<<dim3(128, 8, 4), 256, 0, stream>>>(C, CT);
    gemm_kernel<<<2048, 256, 0, stream>>>(Wn, CT, out, la);
    fixch1_kernel<<<dim3(L_ / 256, B_), 256, 0, stream>>>(x, conv_w, h_w, out, la);
    logscan_kernel<<<B_ * CH_, 256, 0, stream>>>(la, out);
}

// Round 10
// 217.788 us; speedup vs baseline: 3.0113x; 1.0536x over previous
//
#include <hip/hip_runtime.h>
#include <hip/hip_bf16.h>
#include <math.h>

typedef float f32x4 __attribute__((ext_vector_type(4)));
typedef short s16x8 __attribute__((ext_vector_type(8)));
typedef short s16x16 __attribute__((ext_vector_type(16)));

#define B_  4
#define D_  512
#define L_  8192
#define CH_ 512
#define M_  1024   // interleaved (h,g) rows

__device__ __forceinline__ unsigned short f2bf(float f) {
    union { float f; unsigned u; } v; v.f = f;
    unsigned r = v.u + 0x7FFFu + ((v.u >> 16) & 1u);
    return (unsigned short)(r >> 16);
}

// ---------------------------------------------------------------------------
// Kernel 1: normalize h_w / g_w rows, interleave into Wn[1024][512] bf16.
// ---------------------------------------------------------------------------
__global__ __launch_bounds__(256)
void prep_kernel(const float* __restrict__ h_w, const float* __restrict__ g_w,
                 unsigned short* __restrict__ Wn) {
    __shared__ float red[4];
    const int ch = blockIdx.x, t = threadIdx.x;
    {
        float v0 = h_w[ch * 512 + t], v1 = h_w[ch * 512 + t + 256];
        float ss = v0 * v0 + v1 * v1;
        #pragma unroll
        for (int off = 32; off > 0; off >>= 1) ss += __shfl_down(ss, off, 64);
        if ((t & 63) == 0) red[t >> 6] = ss;
        __syncthreads();
        float tot = red[0] + red[1] + red[2] + red[3];
        float scale = 1.f / (sqrtf(tot) + 1e-4f * sqrtf(512.f));
        Wn[(size_t)(2 * ch) * 512 + t]       = f2bf(v0 * scale);
        Wn[(size_t)(2 * ch) * 512 + t + 256] = f2bf(v1 * scale);
    }
    __syncthreads();
    if (ch >= 2) {
        float v0 = g_w[(ch - 2) * 512 + t], v1 = g_w[(ch - 2) * 512 + t + 256];
        float ss = v0 * v0 + v1 * v1;
        #pragma unroll
        for (int off = 32; off > 0; off >>= 1) ss += __shfl_down(ss, off, 64);
        if ((t & 63) == 0) red[t >> 6] = ss;
        __syncthreads();
        float tot = red[0] + red[1] + red[2] + red[3];
        float scale = 1.f / (sqrtf(tot) + 1e-4f * sqrtf(512.f));
        Wn[(size_t)(2 * ch + 1) * 512 + t]       = f2bf(v0 * scale);
        Wn[(size_t)(2 * ch + 1) * 512 + t + 256] = f2bf(v1 * scale);
    } else {
        Wn[(size_t)(2 * ch + 1) * 512 + t]       = 0;
        Wn[(size_t)(2 * ch + 1) * 512 + t + 256] = 0;
    }
}

// ---------------------------------------------------------------------------
// Kernel 2: depthwise 5-tap conv, pad=2, bf16 out into C[b][d][l] (in d_out).
// ---------------------------------------------------------------------------
__global__ __launch_bounds__(256)
void conv_kernel(const float* __restrict__ x, const float* __restrict__ cw,
                 unsigned short* __restrict__ C) {
    __shared__ float xs[8200];
    const int row = blockIdx.x;          // b*512 + d
    const int d   = row & 511;
    const int t   = threadIdx.x;
    const float* xr = x + (size_t)row * L_;
    #pragma unroll
    for (int i = 0; i < 8; ++i) {
        float4 v = *(const float4*)&xr[(i * 256 + t) * 4];
        *(float4*)&xs[4 + (i * 256 + t) * 4] = v;
    }
    if (t < 4) xs[t] = 0.f;
    if (t >= 252) xs[8196 + (t - 252)] = 0.f;
    float w0 = cw[d * 5 + 0], w1 = cw[d * 5 + 1], w2 = cw[d * 5 + 2],
          w3 = cw[d * 5 + 3], w4 = cw[d * 5 + 4];
    float ss = w0 * w0 + w1 * w1 + w2 * w2 + w3 * w3 + w4 * w4;
    float scale = 1.f / (sqrtf(ss) + 1e-4f * sqrtf(5.f));
    w0 *= scale; w1 *= scale; w2 *= scale; w3 *= scale; w4 *= scale;
    __syncthreads();
    #pragma unroll
    for (int i = 0; i < 32; ++i) {
        int l = i * 256 + t;
        float acc = w0 * xs[l + 2] + w1 * xs[l + 3] + w2 * xs[l + 4]
                  + w3 * xs[l + 5] + w4 * xs[l + 6];
        C[(size_t)row * L_ + l] = f2bf(acc);
    }
}

// ---------------------------------------------------------------------------
// Kernel 2b: transpose C[b][512][8192] -> CT[(b*8192+l)][512] (bf16).
// ---------------------------------------------------------------------------
__global__ __launch_bounds__(256)
void transpose_kernel(const unsigned short* __restrict__ C,
                      unsigned short* __restrict__ CT) {
    __shared__ unsigned short tile[64 * 72];
    const int t  = threadIdx.x;
    const int l0 = blockIdx.x * 64, d0 = blockIdx.y * 64, b = blockIdx.z;
    {
        int r = t >> 2, seg = t & 3;
        s16x16 v = *(const s16x16*)&C[(size_t)(b * 512 + d0 + r) * L_ + l0 + seg * 16];
        *(s16x16*)&tile[r * 72 + seg * 16] = v;
    }
    __syncthreads();
    {
        int lr = t >> 2, seg = t & 3;
        unsigned short tmp[16];
        #pragma unroll
        for (int j = 0; j < 16; ++j) tmp[j] = tile[(seg * 16 + j) * 72 + lr];
        *(s16x16*)&CT[(size_t)(b * 8192 + l0 + lr) * 512 + d0 + seg * 16] =
            *(const s16x16*)tmp;
    }
}

// ---------------------------------------------------------------------------
// Kernel 3: bf16 MFMA GEMM, 128x128 tile, BK=32, 4 waves (64x64 each).
// Epilogue: hardware __expf/__logf -> (zb, la-with-sign) log-space outputs.
// ---------------------------------------------------------------------------
__global__ __launch_bounds__(256)
void gemm_kernel(const unsigned short* __restrict__ Wn,
                 const unsigned short* __restrict__ CT,
                 float* __restrict__ ZB, float* __restrict__ LA) {
    __shared__ unsigned short As[128 * 40];   // [row][k] stride 40 (2-way banks)
    __shared__ unsigned short Bs[128 * 40];
    const int t = threadIdx.x;
    const int lane = t & 63, w = t >> 6;
    const int wgid = ((blockIdx.x & 7) << 8) | (blockIdx.x >> 3);
    const int mBase = (wgid & 7) * 128;
    const int nBase = (wgid >> 3) * 128;

    const int srow = t >> 2, sq = t & 3;
    const int wrow = (w >> 1) * 64, wcol = (w & 1) * 64;

    f32x4 acc[4][4];
    #pragma unroll
    for (int fr = 0; fr < 4; ++fr)
        #pragma unroll
        for (int fc = 0; fc < 4; ++fc)
            acc[fr][fc] = (f32x4){0.f, 0.f, 0.f, 0.f};

    const unsigned short* aP0 = &Wn[(size_t)(mBase + srow) * 512 + sq * 8];
    const unsigned short* aP1 = &Wn[(size_t)(mBase + 64 + srow) * 512 + sq * 8];
    const unsigned short* bP0 = &CT[(size_t)(nBase + srow) * 512 + sq * 8];
    const unsigned short* bP1 = &CT[(size_t)(nBase + 64 + srow) * 512 + sq * 8];

    s16x8 a0v = *(const s16x8*)aP0;
    s16x8 a1v = *(const s16x8*)aP1;
    s16x8 b0v = *(const s16x8*)bP0;
    s16x8 b1v = *(const s16x8*)bP1;

    unsigned short* wA0 = &As[srow * 40 + sq * 8];
    unsigned short* wA1 = &As[(64 + srow) * 40 + sq * 8];
    unsigned short* wB0 = &Bs[srow * 40 + sq * 8];
    unsigned short* wB1 = &Bs[(64 + srow) * 40 + sq * 8];

    #pragma unroll
    for (int ks = 0; ks < 16; ++ks) {
        *(s16x8*)wA0 = a0v;
        *(s16x8*)wA1 = a1v;
        *(s16x8*)wB0 = b0v;
        *(s16x8*)wB1 = b1v;
        __syncthreads();
        if (ks < 15) {
            const int k0 = (ks + 1) * 32;
            a0v = *(const s16x8*)(aP0 + k0);
            a1v = *(const s16x8*)(aP1 + k0);
            b0v = *(const s16x8*)(bP0 + k0);
            b1v = *(const s16x8*)(bP1 + k0);
        }
        s16x8 af[4], bf[4];
        #pragma unroll
        for (int f = 0; f < 4; ++f) {
            af[f] = *(const s16x8*)&As[(wrow + f * 16 + (lane & 15)) * 40 + (lane >> 4) * 8];
            bf[f] = *(const s16x8*)&Bs[(wcol + f * 16 + (lane & 15)) * 40 + (lane >> 4) * 8];
        }
        #pragma unroll
        for (int fr = 0; fr < 4; ++fr)
            #pragma unroll
            for (int fc = 0; fc < 4; ++fc)
                acc[fr][fc] = __builtin_amdgcn_mfma_f32_16x16x32_bf16(
                    af[fr], bf[fc], acc[fr][fc], 0, 0, 0);
        __syncthreads();
    }

    #pragma unroll
    for (int fr = 0; fr < 4; ++fr)
    #pragma unroll
    for (int fc = 0; fc < 4; ++fc) {
        f32x4 a = acc[fr][fc];
        const int gR0 = mBase + wrow + fr * 16 + ((lane >> 4) * 4);
        const int n   = nBase + wcol + fc * 16 + (lane & 15);
        const int bb  = n >> 13, l = n & 8191;
        #pragma unroll
        for (int p = 0; p < 2; ++p) {
            float hv = a[2 * p], gv = a[2 * p + 1];
            const int ch = (gR0 >> 1) + p;
            if (ch == 0)      gv = -1000.f;
            else if (ch == 1) gv =  1000.f;
            float e  = __expf(-fabsf(gv));
            float l1 = __logf(1.f + e);                 // log1p(exp(-|g|))
            float la = fminf(-gv, 0.f) - l1;            // logsig(-g) <= 0
            float ls = fminf(gv, 0.f) - l1;             // logsig(g)
            float zb = ls + __logf(fmaxf(fabsf(hv), 1e-6f));
            float enc = (hv < 0.f) ? fabsf(la) : -fabsf(la);
            size_t off = ((size_t)bb * CH_ + ch) * L_ + l;
            ZB[off] = zb;
            LA[off] = enc;
        }
    }
}

// ---------------------------------------------------------------------------
// Kernel 3b: recompute h[b][1][:] in full f32, rewrite ch1's (la, zb).
// R9 FIX: VGPR=44 showed the x8 "unroll" never batched loads (compiler
// re-serialized to ~8 in flight -> 480 GB/s, 87 us).  Now: explicit
// xv[16][5] load phase (80 loads in flight, ~110 VGPR) + 256 blocks x 128
// thr (every CU gets work).  cv/acc expressions and ascending-d order are
// byte-identical to r7/r8 -> bit-identical h1 (ch1 0.5-ULP grid safe).
// ---------------------------------------------------------------------------
__global__ __launch_bounds__(128)
void fixch1_kernel(const float* __restrict__ x, const float* __restrict__ cw,
                   const float* __restrict__ h_w,
                   float* __restrict__ ZB, float* __restrict__ LA) {
    __shared__ float wc[512][5];
    __shared__ float w1n[512];
    __shared__ float red[2];
    const int b = blockIdx.y;
    const int l = blockIdx.x * 128 + threadIdx.x;
    const int t = threadIdx.x;
    const int lane = t & 63, wid = t >> 6;
    for (int d = t; d < 512; d += 128) {
        float a0 = cw[d * 5 + 0], a1 = cw[d * 5 + 1], a2 = cw[d * 5 + 2],
              a3 = cw[d * 5 + 3], a4 = cw[d * 5 + 4];
        float ss = a0 * a0 + a1 * a1 + a2 * a2 + a3 * a3 + a4 * a4;
        float sc = 1.f / (sqrtf(ss) + 1e-4f * sqrtf(5.f));
        wc[d][0] = a0 * sc; wc[d][1] = a1 * sc; wc[d][2] = a2 * sc;
        wc[d][3] = a3 * sc; wc[d][4] = a4 * sc;
    }
    {
        float v0 = h_w[512 + t],       v1 = h_w[512 + t + 128];
        float v2 = h_w[512 + t + 256], v3 = h_w[512 + t + 384];
        float ss = v0 * v0 + v1 * v1 + v2 * v2 + v3 * v3;
        #pragma unroll
        for (int off = 32; off > 0; off >>= 1) ss += __shfl_down(ss, off, 64);
        if (lane == 0) red[wid] = ss;
        __syncthreads();
        float tot = red[0] + red[1];
        float sc = 1.f / (sqrtf(tot) + 1e-4f * sqrtf(512.f));
        w1n[t]       = v0 * sc;
        w1n[t + 128] = v1 * sc;
        w1n[t + 256] = v2 * sc;
        w1n[t + 384] = v3 * sc;
    }
    __syncthreads();
    const float* xb = x + (size_t)b * D_ * L_;
    const bool lo2 = (l >= 2), lo1 = (l >= 1);
    const bool hi1 = (l + 1 < L_), hi2 = (l + 2 < L_);
    float acc = 0.f;
    for (int d0 = 0; d0 < 512; d0 += 16) {
        float xv[16][5];
        #pragma unroll
        for (int u = 0; u < 16; ++u) {
            const float* xr = xb + (size_t)(d0 + u) * L_;
            xv[u][0] = lo2 ? xr[l - 2] : 0.f;
            xv[u][1] = lo1 ? xr[l - 1] : 0.f;
            xv[u][2] = xr[l];
            xv[u][3] = hi1 ? xr[l + 1] : 0.f;
            xv[u][4] = hi2 ? xr[l + 2] : 0.f;
        }
        #pragma unroll
        for (int u = 0; u < 16; ++u) {
            float cv = wc[d0 + u][0] * xv[u][0] + wc[d0 + u][1] * xv[u][1]
                     + wc[d0 + u][2] * xv[u][2] + wc[d0 + u][3] * xv[u][3]
                     + wc[d0 + u][4] * xv[u][4];
            acc += w1n[d0 + u] * cv;
        }
    }
    size_t off = ((size_t)b * CH_ + 1) * L_ + l;
    LA[off] = (acc < 0.f) ? 1000.f : -1000.f;    // la=-1000, sign(h) packed
    ZB[off] = logf(fmaxf(fabsf(acc), 1e-6f));    // logsig(1000)=0
}

// ---------------------------------------------------------------------------
// Kernel 4: log-space scan from precomputed (la_enc, zb).
// ---------------------------------------------------------------------------
struct LV { float re, sg; };

__device__ __forceinline__ LV lcomb(LV a, LV b) {
    float m  = fmaxf(a.re, b.re);
    float ms = (m > -3.0e38f) ? m : 0.f;
    float s  = a.sg * __expf(a.re - ms) + b.sg * __expf(b.re - ms);
    LV r;
    r.re = ms + __logf(fabsf(s));
    r.sg = (s < 0.f) ? -1.f : 1.f;
    return r;
}

__global__ __launch_bounds__(256)
void logscan_kernel(const float* __restrict__ LA, float* __restrict__ ZO) {
    __shared__ float wA[4];
    __shared__ float wRe[4], wSg[4];
    const int row = blockIdx.x;
    const int t = threadIdx.x;
    const int lane = t & 63, wid = t >> 6;
    const float* ep = LA + (size_t)row * L_;
    float* zp = ZO + (size_t)row * L_;

    float As[32];
    unsigned sgb = 0;
    float run = 0.f;
    #pragma unroll
    for (int i = 0; i < 8; ++i) {
        float4 e4 = *(const float4*)&ep[t * 32 + i * 4];
        float ev0 = e4.x, ev1 = e4.y, ev2 = e4.z, ev3 = e4.w;
        if (!(__float_as_uint(ev0) >> 31)) sgb |= (1u << (i * 4 + 0));
        if (!(__float_as_uint(ev1) >> 31)) sgb |= (1u << (i * 4 + 1));
        if (!(__float_as_uint(ev2) >> 31)) sgb |= (1u << (i * 4 + 2));
        if (!(__float_as_uint(ev3) >> 31)) sgb |= (1u << (i * 4 + 3));
        run -= fabsf(ev0); As[i * 4 + 0] = run;
        run -= fabsf(ev1); As[i * 4 + 1] = run;
        run -= fabsf(ev2); As[i * 4 + 2] = run;
        run -= fabsf(ev3); As[i * 4 + 3] = run;
    }
    float wsc = run;
    #pragma unroll
    for (int off = 1; off < 64; off <<= 1) {
        float u = __shfl_up(wsc, off, 64);
        if (lane >= off) wsc += u;
    }
    if (lane == 63) wA[wid] = wsc;
    __syncthreads();
    float pre = wsc - run;
    for (int j = 0; j < wid; ++j) pre += wA[j];
    #pragma unroll
    for (int i = 0; i < 32; ++i) As[i] += pre;

    float zz[32];
    LV tot = { -INFINITY, 1.f };
    #pragma unroll
    for (int i = 0; i < 8; ++i) {
        float4 z4 = *(const float4*)&zp[t * 32 + i * 4];
        float zv0 = z4.x, zv1 = z4.y, zv2 = z4.z, zv3 = z4.w;
        #pragma unroll
        for (int j = 0; j < 4; ++j) {
            int k = i * 4 + j;
            float zvj = (j == 0) ? zv0 : (j == 1) ? zv1 : (j == 2) ? zv2 : zv3;
            zz[k] = zvj - As[k];
            LV zi = { zz[k], ((sgb >> k) & 1) ? -1.f : 1.f };
            tot = lcomb(tot, zi);
        }
    }
    LV sc = tot;
    #pragma unroll
    for (int off = 1; off < 64; off <<= 1) {
        float ure = __shfl_up(sc.re, off, 64);
        float usg = __shfl_up(sc.sg, off, 64);
        if (lane >= off) { LV u = { ure, usg }; sc = lcomb(u, sc); }
    }
    if (lane == 63) { wRe[wid] = sc.re; wSg[wid] = sc.sg; }
    __syncthreads();
    float pr = __shfl_up(sc.re, 1, 64);
    float ps = __shfl_up(sc.sg, 1, 64);
    LV lex = { -INFINITY, 1.f };
    if (lane != 0) { lex.re = pr; lex.sg = ps; }
    LV wpre = { -INFINITY, 1.f };
    for (int j = 0; j < wid; ++j) { LV u = { wRe[j], wSg[j] }; wpre = lcomb(wpre, u); }
    LV pref = lcomb(wpre, lex);

    LV run2 = pref;
    #pragma unroll
    for (int i = 0; i < 8; ++i) {
        float4 o4;
        #pragma unroll
        for (int j = 0; j < 4; ++j) {
            int k = i * 4 + j;
            LV zi = { zz[k], ((sgb >> k) & 1) ? -1.f : 1.f };
            run2 = lcomb(run2, zi);
            float ov = run2.sg * __expf(As[k] + run2.re);
            if (j == 0) o4.x = ov; else if (j == 1) o4.y = ov;
            else if (j == 2) o4.z = ov; else o4.w = ov;
        }
        *(float4*)&zp[t * 32 + i * 4] = o4;
    }
}

// ---------------------------------------------------------------------------
extern "C" void kernel_launch(void* const* d_in, const int* in_sizes, int n_in,
                              void* d_out, int out_size, void* d_ws, size_t ws_size,
                              hipStream_t stream) {
    const float* x      = (const float*)d_in[0];
    const float* conv_w = (const float*)d_in[1];
    const float* h_w    = (const float*)d_in[2];
    const float* g_w    = (const float*)d_in[3];
    float* out = (float*)d_out;
    char* ws = (char*)d_ws;

    // ws layout (97 MB): CT bf16 [32768][512] = 32MB | Wn bf16 1MB | LA f32 64MB
    unsigned short* CT  = (unsigned short*)ws;
    unsigned short* Wn  = (unsigned short*)(ws + (size_t)32 * 1024 * 1024);
    float*          la  = (float*)(ws + (size_t)33 * 1024 * 1024);
    unsigned short* C   = (unsigned short*)d_out;

    prep_kernel<<<512, 256, 0, stream>>>(h_w, g_w, Wn);
    conv_kernel<<<B_ * D_, 256, 0, stream>>>(x, conv_w, C);
    transpose_kernel<<<dim3(128, 8, 4), 256, 0, stream>>>(C, CT);
    gemm_kernel<<<2048, 256, 0, stream>>>(Wn, CT, out, la);
    fixch1_kernel<<<dim3(L_ / 128, B_), 128, 0, stream>>>(x, conv_w, h_w, out, la);
    logscan_kernel<<<B_ * CH_, 256, 0, stream>>>(la, out);
}